// Round 1
// baseline (3083.310 us; speedup 1.0000x reference)
//
#include <hip/hip_runtime.h>

#define N_NODES 50000
#define DIM 128
#define NEDGE 800000
#define NGRAPH 100
#define NPG 500   // nodes per graph

// ---------------- GEMM: C[n,128] = A[n,128] @ W[128,128] ----------------
// W staged fully in LDS (64 KB). 256 threads = 2 rows x 128 cols, grid-stride.
__global__ void gemm128(const float* __restrict__ A, const float* __restrict__ W,
                        float* __restrict__ C, int n) {
    __shared__ float Wl[DIM * DIM];
    for (int i = threadIdx.x; i < DIM * DIM; i += blockDim.x) Wl[i] = W[i];
    __syncthreads();
    const int col = threadIdx.x & 127;
    const int rowInBlk = threadIdx.x >> 7;          // 0..1
    const int rowsPerBlk = blockDim.x >> 7;         // 2
    for (int row = blockIdx.x * rowsPerBlk + rowInBlk; row < n;
         row += gridDim.x * rowsPerBlk) {
        const float* a = A + (size_t)row * DIM;
        float acc = 0.f;
#pragma unroll 16
        for (int k = 0; k < DIM; ++k)
            acc = fmaf(a[k], Wl[k * DIM + col], acc);
        C[(size_t)row * DIM + col] = acc;
    }
}

// ---------------- edge scatter: agg[dst] += w * msg[src], 128-dim --------
// 32-lane group per edge, float4 per lane, 4 scalar atomics.
__global__ void scatter_feat(const float* __restrict__ msg, const int* __restrict__ src,
                             const int* __restrict__ dst, const float* __restrict__ w,
                             float* __restrict__ agg, int E) {
    int gid = blockIdx.x * blockDim.x + threadIdx.x;
    int grp = gid >> 5, lane = gid & 31;
    int ngrp = (gridDim.x * blockDim.x) >> 5;
    for (int e = grp; e < E; e += ngrp) {
        int s = src[e], d = dst[e];
        float we = w[e];
        float4 v = ((const float4*)(msg + (size_t)s * DIM))[lane];
        float* o = agg + (size_t)d * DIM + lane * 4;
        atomicAdd(o + 0, v.x * we);
        atomicAdd(o + 1, v.y * we);
        atomicAdd(o + 2, v.z * we);
        atomicAdd(o + 3, v.w * we);
    }
}

// ---------------- h = relu(h + b) ----------------
__global__ void bias_relu(float* __restrict__ h, const float* __restrict__ b, int n4) {
    int i = blockIdx.x * blockDim.x + threadIdx.x;
    int stride = gridDim.x * blockDim.x;
    for (; i < n4; i += stride) {
        float4 v = ((float4*)h)[i];
        int f = (i & 31) * 4;   // feature offset within the 128-dim row
        v.x = fmaxf(v.x + b[f + 0], 0.f);
        v.y = fmaxf(v.y + b[f + 1], 0.f);
        v.z = fmaxf(v.z + b[f + 2], 0.f);
        v.w = fmaxf(v.w + b[f + 3], 0.f);
        ((float4*)h)[i] = v;
    }
}

// ---------------- s[node] = dot(h2[node,:], Wf[:,0]) ----------------
__global__ void dot_wf(const float* __restrict__ h, const float* __restrict__ wf,
                       float* __restrict__ s, int n) {
    int gid = blockIdx.x * blockDim.x + threadIdx.x;
    int grp = gid >> 5, lane = gid & 31;
    int ngrp = (gridDim.x * blockDim.x) >> 5;
    for (int node = grp; node < n; node += ngrp) {
        float4 a = ((const float4*)(h + (size_t)node * DIM))[lane];
        float4 b = ((const float4*)wf)[lane];
        float d = a.x * b.x + a.y * b.y + a.z * b.z + a.w * b.w;
#pragma unroll
        for (int off = 16; off; off >>= 1) d += __shfl_down(d, off, 32);
        if (lane == 0) s[node] = d;
    }
}

// ---------------- scalar scatter: agg[dst] += w * s[src] ----------------
__global__ void scatter_scalar(const float* __restrict__ s, const int* __restrict__ src,
                               const int* __restrict__ dst, const float* __restrict__ w,
                               float* __restrict__ agg, int E) {
    int i = blockIdx.x * blockDim.x + threadIdx.x;
    int stride = gridDim.x * blockDim.x;
    for (; i < E; i += stride)
        atomicAdd(&agg[dst[i]], w[i] * s[src[i]]);
}

// ---------------- out[g] = mean over graph of sigmoid(agg + bf) ----------
__global__ void readout(const float* __restrict__ agg, const float* __restrict__ bfp,
                        float* __restrict__ out) {
    __shared__ float red[256];
    int g = blockIdx.x;
    float bf = bfp[0];
    float sum = 0.f;
    for (int i = threadIdx.x; i < NPG; i += blockDim.x) {
        float v = agg[g * NPG + i] + bf;
        sum += 1.f / (1.f + expf(-v));
    }
    red[threadIdx.x] = sum;
    __syncthreads();
    for (int s = 128; s > 0; s >>= 1) {
        if (threadIdx.x < s) red[threadIdx.x] += red[threadIdx.x + s];
        __syncthreads();
    }
    if (threadIdx.x == 0) out[g] = red[0] / (float)NPG;
}

extern "C" void kernel_launch(void* const* d_in, const int* in_sizes, int n_in,
                              void* d_out, int out_size, void* d_ws, size_t ws_size,
                              hipStream_t stream) {
    const float* X  = (const float*)d_in[0];
    const float* ew = (const float*)d_in[1];
    const float* W1 = (const float*)d_in[2];
    const float* b1 = (const float*)d_in[3];
    const float* W2 = (const float*)d_in[4];
    const float* b2 = (const float*)d_in[5];
    const float* Wf = (const float*)d_in[6];
    const float* bf = (const float*)d_in[7];
    const int* ei   = (const int*)d_in[8];
    const int* src  = ei;
    const int* dst  = ei + NEDGE;

    float* out = (float*)d_out;

    // workspace layout
    char* ws = (char*)d_ws;
    float* bufA    = (float*)ws;                                  // N*128
    float* bufB    = (float*)(ws + (size_t)N_NODES * DIM * 4);    // N*128
    float* s_node  = (float*)(ws + (size_t)2 * N_NODES * DIM * 4);// N
    float* nodeagg = s_node + N_NODES;                            // N

    const int TB = 256;
    const int GRID = 2048;
    const size_t featBytes = (size_t)N_NODES * DIM * sizeof(float);

    // ---- layer 1 ----
    gemm128<<<GRID, TB, 0, stream>>>(X, W1, bufA, N_NODES);                  // bufA = X@W1
    hipMemsetAsync(bufB, 0, featBytes, stream);
    scatter_feat<<<GRID, TB, 0, stream>>>(bufA, src, dst, ew, bufB, NEDGE);  // bufB = A@(X W1)
    bias_relu<<<GRID, TB, 0, stream>>>(bufB, b1, N_NODES * DIM / 4);         // h1

    // ---- layer 2 ----
    gemm128<<<GRID, TB, 0, stream>>>(bufB, W2, bufA, N_NODES);               // bufA = h1@W2
    hipMemsetAsync(bufB, 0, featBytes, stream);
    scatter_feat<<<GRID, TB, 0, stream>>>(bufA, src, dst, ew, bufB, NEDGE);
    bias_relu<<<GRID, TB, 0, stream>>>(bufB, b2, N_NODES * DIM / 4);         // h2

    // ---- final layer ----
    dot_wf<<<GRID, TB, 0, stream>>>(bufB, Wf, s_node, N_NODES);              // s = h2@Wf
    hipMemsetAsync(nodeagg, 0, (size_t)N_NODES * sizeof(float), stream);
    scatter_scalar<<<GRID, TB, 0, stream>>>(s_node, src, dst, ew, nodeagg, NEDGE);

    // ---- readout ----
    readout<<<NGRAPH, TB, 0, stream>>>(nodeagg, bf, out);
}

// Round 2
// 518.413 us; speedup vs baseline: 5.9476x; 5.9476x over previous
//
#include <hip/hip_runtime.h>

#define N_NODES 50000
#define DIM 128
#define NEDGE 800000
#define NGRAPH 100
#define NPG 500    // nodes per graph
#define SCAN_CHUNK 196  // ceil(50000/256)

// ---------------- CSR build ----------------
__global__ void hist_kernel(const int* __restrict__ dst, int* __restrict__ cnt, int E) {
    int i = blockIdx.x * blockDim.x + threadIdx.x;
    int stride = gridDim.x * blockDim.x;
    for (; i < E; i += stride) atomicAdd(&cnt[dst[i]], 1);
}

// single block, 256 threads: exclusive scan of cnt[0..N) -> rowptr, cursor
__global__ void scan_kernel(const int* __restrict__ cnt, int* __restrict__ rowptr,
                            int* __restrict__ cursor) {
    __shared__ int part[256];
    int t = threadIdx.x;
    int lo = t * SCAN_CHUNK;
    int hi = min(lo + SCAN_CHUNK, N_NODES);
    int s = 0;
    for (int i = lo; i < hi; ++i) s += cnt[i];
    part[t] = s;
    __syncthreads();
    for (int off = 1; off < 256; off <<= 1) {
        int v = (t >= off) ? part[t - off] : 0;
        __syncthreads();
        part[t] += v;
        __syncthreads();
    }
    int run = part[t] - s;  // exclusive prefix
    for (int i = lo; i < hi; ++i) {
        rowptr[i] = run;
        cursor[i] = run;
        run += cnt[i];
    }
    if (hi == N_NODES) rowptr[N_NODES] = run;
}

__global__ void place_kernel(const int* __restrict__ dst, int* __restrict__ cursor,
                             int* __restrict__ eid, int E) {
    int i = blockIdx.x * blockDim.x + threadIdx.x;
    int stride = gridDim.x * blockDim.x;
    for (; i < E; i += stride) {
        int p = atomicAdd(&cursor[dst[i]], 1);
        eid[p] = i;
    }
}

// ---------------- GEMM: C[n,128] = A[n,128] @ W[128,128] ----------------
// 256 thr = 32 col-groups x 8; each thread does 2 rows x 4 cols. 16 rows/block.
__global__ void gemm128(const float* __restrict__ A, const float* __restrict__ W,
                        float* __restrict__ C) {
    __shared__ float Wl[DIM * DIM];
    for (int i = threadIdx.x; i < DIM * DIM; i += 256) Wl[i] = W[i];
    __syncthreads();
    const int cg = threadIdx.x & 31;
    const int tr = threadIdx.x >> 5;          // 0..7
    const int row0 = blockIdx.x * 16 + tr * 2;  // N divisible by 16 -> no tail
    const float* a0 = A + (size_t)row0 * DIM;
    const float* a1 = a0 + DIM;
    float4 acc0 = {0.f, 0.f, 0.f, 0.f};
    float4 acc1 = {0.f, 0.f, 0.f, 0.f};
#pragma unroll 8
    for (int k = 0; k < DIM; ++k) {
        float4 wv = *(const float4*)(&Wl[k * DIM + cg * 4]);
        float x0 = a0[k], x1 = a1[k];
        acc0.x = fmaf(x0, wv.x, acc0.x); acc0.y = fmaf(x0, wv.y, acc0.y);
        acc0.z = fmaf(x0, wv.z, acc0.z); acc0.w = fmaf(x0, wv.w, acc0.w);
        acc1.x = fmaf(x1, wv.x, acc1.x); acc1.y = fmaf(x1, wv.y, acc1.y);
        acc1.z = fmaf(x1, wv.z, acc1.z); acc1.w = fmaf(x1, wv.w, acc1.w);
    }
    *(float4*)(C + (size_t)row0 * DIM + cg * 4) = acc0;
    *(float4*)(C + (size_t)(row0 + 1) * DIM + cg * 4) = acc1;
}

// ---------------- CSR gather + fused epilogue ----------------
// MODE 0: out_row = relu(agg + bias), write float4 row
// MODE 1: h = relu(agg + bias); outS[v] = dot(h, wf)   (h2 never materialized)
template <int MODE>
__global__ void gather_feat(const float* __restrict__ msg, const int* __restrict__ eid,
                            const int* __restrict__ rowptr, const int* __restrict__ src,
                            const float* __restrict__ w, const float* __restrict__ bias,
                            const float* __restrict__ wf, float* __restrict__ outF,
                            float* __restrict__ outS) {
    int gid = blockIdx.x * blockDim.x + threadIdx.x;
    int grp = gid >> 5, lane = gid & 31;
    if (grp >= N_NODES) return;
    int beg = rowptr[grp], end = rowptr[grp + 1];
    float4 acc = {0.f, 0.f, 0.f, 0.f};
    for (int i = beg; i < end; ++i) {
        int e = eid[i];
        float we = w[e];
        int s = src[e];
        float4 m = ((const float4*)(msg + (size_t)s * DIM))[lane];
        acc.x = fmaf(we, m.x, acc.x);
        acc.y = fmaf(we, m.y, acc.y);
        acc.z = fmaf(we, m.z, acc.z);
        acc.w = fmaf(we, m.w, acc.w);
    }
    float4 b = ((const float4*)bias)[lane];
    acc.x = fmaxf(acc.x + b.x, 0.f);
    acc.y = fmaxf(acc.y + b.y, 0.f);
    acc.z = fmaxf(acc.z + b.z, 0.f);
    acc.w = fmaxf(acc.w + b.w, 0.f);
    if (MODE == 0) {
        ((float4*)(outF + (size_t)grp * DIM))[lane] = acc;
    } else {
        float4 f = ((const float4*)wf)[lane];
        float d = acc.x * f.x + acc.y * f.y + acc.z * f.z + acc.w * f.w;
#pragma unroll
        for (int off = 16; off; off >>= 1) d += __shfl_down(d, off, 32);
        if (lane == 0) outS[grp] = d;
    }
}

// ---------------- nodeagg[v] = sum_in w * s[src] (CSR, no atomics) --------
__global__ void gather_scalar(const float* __restrict__ s, const int* __restrict__ eid,
                              const int* __restrict__ rowptr, const int* __restrict__ src,
                              const float* __restrict__ w, float* __restrict__ nodeagg) {
    int v = blockIdx.x * blockDim.x + threadIdx.x;
    if (v >= N_NODES) return;
    int beg = rowptr[v], end = rowptr[v + 1];
    float a = 0.f;
    for (int i = beg; i < end; ++i) {
        int e = eid[i];
        a += w[e] * s[src[e]];
    }
    nodeagg[v] = a;
}

// ---------------- out[g] = mean over graph of sigmoid(agg + bf) ----------
__global__ void readout(const float* __restrict__ agg, const float* __restrict__ bfp,
                        float* __restrict__ out) {
    __shared__ float red[256];
    int g = blockIdx.x;
    float bf = bfp[0];
    float sum = 0.f;
    for (int i = threadIdx.x; i < NPG; i += blockDim.x) {
        float v = agg[g * NPG + i] + bf;
        sum += 1.f / (1.f + expf(-v));
    }
    red[threadIdx.x] = sum;
    __syncthreads();
    for (int s = 128; s > 0; s >>= 1) {
        if (threadIdx.x < s) red[threadIdx.x] += red[threadIdx.x + s];
        __syncthreads();
    }
    if (threadIdx.x == 0) out[g] = red[0] / (float)NPG;
}

extern "C" void kernel_launch(void* const* d_in, const int* in_sizes, int n_in,
                              void* d_out, int out_size, void* d_ws, size_t ws_size,
                              hipStream_t stream) {
    const float* X  = (const float*)d_in[0];
    const float* ew = (const float*)d_in[1];
    const float* W1 = (const float*)d_in[2];
    const float* b1 = (const float*)d_in[3];
    const float* W2 = (const float*)d_in[4];
    const float* b2 = (const float*)d_in[5];
    const float* Wf = (const float*)d_in[6];
    const float* bf = (const float*)d_in[7];
    const int* ei   = (const int*)d_in[8];
    const int* src  = ei;
    const int* dst  = ei + NEDGE;

    float* out = (float*)d_out;

    // workspace layout (offsets in bytes, 256-aligned)
    char* ws = (char*)d_ws;
    size_t off = 0;
    float* bufA = (float*)(ws + off); off += (size_t)N_NODES * DIM * 4;      // 25.6 MB
    float* bufB = (float*)(ws + off); off += (size_t)N_NODES * DIM * 4;      // 25.6 MB
    int* eid    = (int*)(ws + off);   off += (size_t)NEDGE * 4;              // 3.2 MB
    int* rowptr = (int*)(ws + off);   off += (size_t)(N_NODES + 1 + 63) * 4; // 200 KB
    int* cnt    = (int*)(ws + off);   off += (size_t)N_NODES * 4;
    int* cursor = (int*)(ws + off);   off += (size_t)N_NODES * 4;
    float* s_node  = (float*)(ws + off); off += (size_t)N_NODES * 4;
    float* nodeagg = (float*)(ws + off); off += (size_t)N_NODES * 4;

    const int TB = 256;
    const int EBLK = (NEDGE + TB - 1) / TB;            // 3125
    const int GATHER_BLK = (N_NODES * 32 + TB - 1) / TB;  // 6250
    const int NODE_BLK = (N_NODES + TB - 1) / TB;      // 196

    // ---- CSR build (by dst) ----
    hipMemsetAsync(cnt, 0, (size_t)N_NODES * 4, stream);
    hist_kernel<<<EBLK, TB, 0, stream>>>(dst, cnt, NEDGE);
    scan_kernel<<<1, 256, 0, stream>>>(cnt, rowptr, cursor);
    place_kernel<<<EBLK, TB, 0, stream>>>(dst, cursor, eid, NEDGE);

    // ---- layer 1: h1 = relu(A(X@W1) + b1) ----
    gemm128<<<N_NODES / 16, TB, 0, stream>>>(X, W1, bufA);
    gather_feat<0><<<GATHER_BLK, TB, 0, stream>>>(bufA, eid, rowptr, src, ew, b1,
                                                  nullptr, bufB, nullptr);
    // ---- layer 2 + Wf dot: s = relu(A(h1@W2) + b2) @ Wf ----
    gemm128<<<N_NODES / 16, TB, 0, stream>>>(bufB, W2, bufA);
    gather_feat<1><<<GATHER_BLK, TB, 0, stream>>>(bufA, eid, rowptr, src, ew, b2,
                                                  Wf, nullptr, s_node);
    // ---- final aggregation + readout ----
    gather_scalar<<<NODE_BLK, TB, 0, stream>>>(s_node, eid, rowptr, src, ew, nodeagg);
    readout<<<NGRAPH, TB, 0, stream>>>(nodeagg, bf, out);
}

// Round 3
// 323.261 us; speedup vs baseline: 9.5382x; 1.6037x over previous
//
#include <hip/hip_runtime.h>

#define N_NODES 50000
#define DIM 128
#define NEDGE 800000
#define NGRAPH 100
#define NPG 500    // nodes per graph
#define NB_SCAN 196  // ceil(50000/256)

// ---------------- CSR build ----------------
__global__ void hist_kernel(const int* __restrict__ dst, int* __restrict__ cnt, int E) {
    int i = blockIdx.x * blockDim.x + threadIdx.x;
    int stride = gridDim.x * blockDim.x;
    for (; i < E; i += stride) atomicAdd(&cnt[dst[i]], 1);
}

// phase A: per-block sums of cnt
__global__ void scan_phaseA(const int* __restrict__ cnt, int* __restrict__ blkSum) {
    __shared__ int red[256];
    int i = blockIdx.x * 256 + threadIdx.x;
    int v = (i < N_NODES) ? cnt[i] : 0;
    red[threadIdx.x] = v;
    __syncthreads();
    for (int s = 128; s > 0; s >>= 1) {
        if (threadIdx.x < s) red[threadIdx.x] += red[threadIdx.x + s];
        __syncthreads();
    }
    if (threadIdx.x == 0) blkSum[blockIdx.x] = red[0];
}

// phase B: single block, exclusive scan of blkSum[0..nb)
__global__ void scan_phaseB(int* __restrict__ blkSum, int nb) {
    __shared__ int sh[256];
    int t = threadIdx.x;
    int v = (t < nb) ? blkSum[t] : 0;
    sh[t] = v;
    __syncthreads();
    for (int off = 1; off < 256; off <<= 1) {
        int u = (t >= off) ? sh[t - off] : 0;
        __syncthreads();
        sh[t] += u;
        __syncthreads();
    }
    if (t < nb) blkSum[t] = sh[t] - v;  // exclusive
}

// phase C: intra-block exclusive scan + block offset -> rowptr, cursor
__global__ void scan_phaseC(const int* __restrict__ cnt, const int* __restrict__ blkSum,
                            int* __restrict__ rowptr, int* __restrict__ cursor) {
    __shared__ int sh[256];
    int t = threadIdx.x;
    int i = blockIdx.x * 256 + t;
    int v = (i < N_NODES) ? cnt[i] : 0;
    sh[t] = v;
    __syncthreads();
    for (int off = 1; off < 256; off <<= 1) {
        int u = (t >= off) ? sh[t - off] : 0;
        __syncthreads();
        sh[t] += u;
        __syncthreads();
    }
    int excl = blkSum[blockIdx.x] + sh[t] - v;
    if (i < N_NODES) {
        rowptr[i] = excl;
        cursor[i] = excl;
        if (i == N_NODES - 1) rowptr[N_NODES] = excl + v;
    }
}

// place: packed {src, weight} directly at the CSR slot
__global__ void place_kernel(const int* __restrict__ src, const int* __restrict__ dst,
                             const float* __restrict__ w, int* __restrict__ cursor,
                             int2* __restrict__ pack, int E) {
    int i = blockIdx.x * blockDim.x + threadIdx.x;
    int stride = gridDim.x * blockDim.x;
    for (; i < E; i += stride) {
        int p = atomicAdd(&cursor[dst[i]], 1);
        pack[p] = make_int2(src[i], __float_as_int(w[i]));
    }
}

// ---------------- GEMM: C[n,128] = A[n,128] @ W[128,128] ----------------
__global__ void gemm128(const float* __restrict__ A, const float* __restrict__ W,
                        float* __restrict__ C) {
    __shared__ float Wl[DIM * DIM];
    for (int i = threadIdx.x; i < DIM * DIM; i += 256) Wl[i] = W[i];
    __syncthreads();
    const int cg = threadIdx.x & 31;
    const int tr = threadIdx.x >> 5;            // 0..7
    const int row0 = blockIdx.x * 16 + tr * 2;  // N divisible by 16 -> no tail
    const float* a0 = A + (size_t)row0 * DIM;
    const float* a1 = a0 + DIM;
    float4 acc0 = {0.f, 0.f, 0.f, 0.f};
    float4 acc1 = {0.f, 0.f, 0.f, 0.f};
#pragma unroll 8
    for (int k = 0; k < DIM; ++k) {
        float4 wv = *(const float4*)(&Wl[k * DIM + cg * 4]);
        float x0 = a0[k], x1 = a1[k];
        acc0.x = fmaf(x0, wv.x, acc0.x); acc0.y = fmaf(x0, wv.y, acc0.y);
        acc0.z = fmaf(x0, wv.z, acc0.z); acc0.w = fmaf(x0, wv.w, acc0.w);
        acc1.x = fmaf(x1, wv.x, acc1.x); acc1.y = fmaf(x1, wv.y, acc1.y);
        acc1.z = fmaf(x1, wv.z, acc1.z); acc1.w = fmaf(x1, wv.w, acc1.w);
    }
    *(float4*)(C + (size_t)row0 * DIM + cg * 4) = acc0;
    *(float4*)(C + (size_t)(row0 + 1) * DIM + cg * 4) = acc1;
}

// ---------------- CSR gather + fused epilogue ----------------
// MODE 0: out_row = relu(agg + bias), write float4 row
// MODE 1: h = relu(agg + bias); outS[v] = dot(h, wf)
template <int MODE>
__global__ void gather_feat(const float* __restrict__ msg, const int2* __restrict__ pack,
                            const int* __restrict__ rowptr, const float* __restrict__ bias,
                            const float* __restrict__ wf, float* __restrict__ outF,
                            float* __restrict__ outS) {
    int gid = blockIdx.x * blockDim.x + threadIdx.x;
    int grp = gid >> 5, lane = gid & 31;
    if (grp >= N_NODES) return;
    int beg = rowptr[grp], end = rowptr[grp + 1];
    float4 acc = {0.f, 0.f, 0.f, 0.f};
    int i = beg;
    for (; i + 1 < end; i += 2) {   // 2 independent gather chains
        int2 p0 = pack[i], p1 = pack[i + 1];
        float w0 = __int_as_float(p0.y), w1 = __int_as_float(p1.y);
        float4 m0 = ((const float4*)(msg + (size_t)p0.x * DIM))[lane];
        float4 m1 = ((const float4*)(msg + (size_t)p1.x * DIM))[lane];
        acc.x = fmaf(w0, m0.x, acc.x); acc.y = fmaf(w0, m0.y, acc.y);
        acc.z = fmaf(w0, m0.z, acc.z); acc.w = fmaf(w0, m0.w, acc.w);
        acc.x = fmaf(w1, m1.x, acc.x); acc.y = fmaf(w1, m1.y, acc.y);
        acc.z = fmaf(w1, m1.z, acc.z); acc.w = fmaf(w1, m1.w, acc.w);
    }
    if (i < end) {
        int2 p0 = pack[i];
        float w0 = __int_as_float(p0.y);
        float4 m0 = ((const float4*)(msg + (size_t)p0.x * DIM))[lane];
        acc.x = fmaf(w0, m0.x, acc.x); acc.y = fmaf(w0, m0.y, acc.y);
        acc.z = fmaf(w0, m0.z, acc.z); acc.w = fmaf(w0, m0.w, acc.w);
    }
    float4 b = ((const float4*)bias)[lane];
    acc.x = fmaxf(acc.x + b.x, 0.f);
    acc.y = fmaxf(acc.y + b.y, 0.f);
    acc.z = fmaxf(acc.z + b.z, 0.f);
    acc.w = fmaxf(acc.w + b.w, 0.f);
    if (MODE == 0) {
        ((float4*)(outF + (size_t)grp * DIM))[lane] = acc;
    } else {
        float4 f = ((const float4*)wf)[lane];
        float d = acc.x * f.x + acc.y * f.y + acc.z * f.z + acc.w * f.w;
#pragma unroll
        for (int off = 16; off; off >>= 1) d += __shfl_down(d, off, 32);
        if (lane == 0) outS[grp] = d;
    }
}

// ---------------- nodeagg[v] = sum_in w * s[src] (CSR, no atomics) --------
__global__ void gather_scalar(const float* __restrict__ s, const int2* __restrict__ pack,
                              const int* __restrict__ rowptr, float* __restrict__ nodeagg) {
    int v = blockIdx.x * blockDim.x + threadIdx.x;
    if (v >= N_NODES) return;
    int beg = rowptr[v], end = rowptr[v + 1];
    float a = 0.f;
    for (int i = beg; i < end; ++i) {
        int2 p = pack[i];
        a += __int_as_float(p.y) * s[p.x];
    }
    nodeagg[v] = a;
}

// ---------------- out[g] = mean over graph of sigmoid(agg + bf) ----------
__global__ void readout(const float* __restrict__ agg, const float* __restrict__ bfp,
                        float* __restrict__ out) {
    __shared__ float red[256];
    int g = blockIdx.x;
    float bf = bfp[0];
    float sum = 0.f;
    for (int i = threadIdx.x; i < NPG; i += blockDim.x) {
        float v = agg[g * NPG + i] + bf;
        sum += 1.f / (1.f + expf(-v));
    }
    red[threadIdx.x] = sum;
    __syncthreads();
    for (int s = 128; s > 0; s >>= 1) {
        if (threadIdx.x < s) red[threadIdx.x] += red[threadIdx.x + s];
        __syncthreads();
    }
    if (threadIdx.x == 0) out[g] = red[0] / (float)NPG;
}

extern "C" void kernel_launch(void* const* d_in, const int* in_sizes, int n_in,
                              void* d_out, int out_size, void* d_ws, size_t ws_size,
                              hipStream_t stream) {
    const float* X  = (const float*)d_in[0];
    const float* ew = (const float*)d_in[1];
    const float* W1 = (const float*)d_in[2];
    const float* b1 = (const float*)d_in[3];
    const float* W2 = (const float*)d_in[4];
    const float* b2 = (const float*)d_in[5];
    const float* Wf = (const float*)d_in[6];
    const float* bf = (const float*)d_in[7];
    const int* ei   = (const int*)d_in[8];
    const int* src  = ei;
    const int* dst  = ei + NEDGE;

    float* out = (float*)d_out;

    // workspace layout
    char* ws = (char*)d_ws;
    size_t off = 0;
    float* bufA = (float*)(ws + off); off += (size_t)N_NODES * DIM * 4;       // 25.6 MB
    float* bufB = (float*)(ws + off); off += (size_t)N_NODES * DIM * 4;       // 25.6 MB
    int2* pack  = (int2*)(ws + off);  off += (size_t)NEDGE * 8;               // 6.4 MB
    int* rowptr = (int*)(ws + off);   off += (size_t)(N_NODES + 64) * 4;
    int* cnt    = (int*)(ws + off);   off += (size_t)N_NODES * 4;
    int* cursor = (int*)(ws + off);   off += (size_t)N_NODES * 4;
    int* blkSum = (int*)(ws + off);   off += (size_t)256 * 4;
    float* s_node  = (float*)(ws + off); off += (size_t)N_NODES * 4;
    float* nodeagg = (float*)(ws + off); off += (size_t)N_NODES * 4;

    const int TB = 256;
    const int EBLK = (NEDGE + TB - 1) / TB;               // 3125
    const int GATHER_BLK = (N_NODES * 32 + TB - 1) / TB;  // 6250
    const int NODE_BLK = (N_NODES + TB - 1) / TB;         // 196

    // ---- CSR build (by dst) ----
    hipMemsetAsync(cnt, 0, (size_t)N_NODES * 4, stream);
    hist_kernel<<<EBLK, TB, 0, stream>>>(dst, cnt, NEDGE);
    scan_phaseA<<<NB_SCAN, TB, 0, stream>>>(cnt, blkSum);
    scan_phaseB<<<1, 256, 0, stream>>>(blkSum, NB_SCAN);
    scan_phaseC<<<NB_SCAN, TB, 0, stream>>>(cnt, blkSum, rowptr, cursor);
    place_kernel<<<EBLK, TB, 0, stream>>>(src, dst, ew, cursor, pack, NEDGE);

    // ---- layer 1: h1 = relu(A(X@W1) + b1) ----
    gemm128<<<N_NODES / 16, TB, 0, stream>>>(X, W1, bufA);
    gather_feat<0><<<GATHER_BLK, TB, 0, stream>>>(bufA, pack, rowptr, b1,
                                                  nullptr, bufB, nullptr);
    // ---- layer 2 + Wf dot: s = relu(A(h1@W2) + b2) @ Wf ----
    gemm128<<<N_NODES / 16, TB, 0, stream>>>(bufB, W2, bufA);
    gather_feat<1><<<GATHER_BLK, TB, 0, stream>>>(bufA, pack, rowptr, b2,
                                                  Wf, nullptr, s_node);
    // ---- final aggregation + readout ----
    gather_scalar<<<NODE_BLK, TB, 0, stream>>>(s_node, pack, rowptr, nodeagg);
    readout<<<NGRAPH, TB, 0, stream>>>(nodeagg, bf, out);
}

// Round 4
// 276.474 us; speedup vs baseline: 11.1523x; 1.1692x over previous
//
#include <hip/hip_runtime.h>
#include <hip/hip_fp16.h>

#define N_NODES 50000
#define DIM 128
#define NEDGE 800000
#define NGRAPH 100
#define NPG 500    // nodes per graph
#define NB_SCAN 196  // ceil(50000/256)

// ---------------- CSR build ----------------
__global__ void hist_kernel(const int* __restrict__ dst, int* __restrict__ cnt, int E) {
    int i = blockIdx.x * blockDim.x + threadIdx.x;
    int stride = gridDim.x * blockDim.x;
    for (; i < E; i += stride) atomicAdd(&cnt[dst[i]], 1);
}

__global__ void scan_phaseA(const int* __restrict__ cnt, int* __restrict__ blkSum) {
    __shared__ int red[256];
    int i = blockIdx.x * 256 + threadIdx.x;
    int v = (i < N_NODES) ? cnt[i] : 0;
    red[threadIdx.x] = v;
    __syncthreads();
    for (int s = 128; s > 0; s >>= 1) {
        if (threadIdx.x < s) red[threadIdx.x] += red[threadIdx.x + s];
        __syncthreads();
    }
    if (threadIdx.x == 0) blkSum[blockIdx.x] = red[0];
}

__global__ void scan_phaseB(int* __restrict__ blkSum, int nb) {
    __shared__ int sh[256];
    int t = threadIdx.x;
    int v = (t < nb) ? blkSum[t] : 0;
    sh[t] = v;
    __syncthreads();
    for (int off = 1; off < 256; off <<= 1) {
        int u = (t >= off) ? sh[t - off] : 0;
        __syncthreads();
        sh[t] += u;
        __syncthreads();
    }
    if (t < nb) blkSum[t] = sh[t] - v;  // exclusive
}

__global__ void scan_phaseC(const int* __restrict__ cnt, const int* __restrict__ blkSum,
                            int* __restrict__ rowptr, int* __restrict__ cursor) {
    __shared__ int sh[256];
    int t = threadIdx.x;
    int i = blockIdx.x * 256 + t;
    int v = (i < N_NODES) ? cnt[i] : 0;
    sh[t] = v;
    __syncthreads();
    for (int off = 1; off < 256; off <<= 1) {
        int u = (t >= off) ? sh[t - off] : 0;
        __syncthreads();
        sh[t] += u;
        __syncthreads();
    }
    int excl = blkSum[blockIdx.x] + sh[t] - v;
    if (i < N_NODES) {
        rowptr[i] = excl;
        cursor[i] = excl;
        if (i == N_NODES - 1) rowptr[N_NODES] = excl + v;
    }
}

// place: packed {src:16, half(weight):16} at the CSR slot (4 B scatter)
__global__ void place_kernel(const int* __restrict__ src, const int* __restrict__ dst,
                             const float* __restrict__ w, int* __restrict__ cursor,
                             unsigned int* __restrict__ pack, int E) {
    int i = blockIdx.x * blockDim.x + threadIdx.x;
    int stride = gridDim.x * blockDim.x;
    for (; i < E; i += stride) {
        int p = atomicAdd(&cursor[dst[i]], 1);
        unsigned short wb = __half_as_ushort(__float2half_rn(w[i]));
        pack[p] = ((unsigned int)src[i] << 16) | (unsigned int)wb;
    }
}

// ---------------- GEMM: C[n,128] = A[n,128] @ W[128,128], C in fp16 -------
// 256 thr: 32 col-groups x 8 row-groups; each thread 4 rows x 4 cols.
template <typename TIN>
__global__ void gemm128(const TIN* __restrict__ A, const float* __restrict__ W,
                        __half* __restrict__ C) {
    __shared__ float Wl[DIM * DIM];
    for (int i = threadIdx.x; i < DIM * DIM; i += 256) Wl[i] = W[i];
    __syncthreads();
    const int cg = threadIdx.x & 31;
    const int tr = threadIdx.x >> 5;            // 0..7
    const int row0 = blockIdx.x * 32 + tr * 4;
    if (row0 >= N_NODES) return;                // N % 4 == 0: all 4 rows valid
    const TIN* a = A + (size_t)row0 * DIM;
    float acc[4][4] = {};
#pragma unroll 4
    for (int k = 0; k < DIM; ++k) {
        float4 wv = *(const float4*)(&Wl[k * DIM + cg * 4]);
        float x0 = (float)a[k];
        float x1 = (float)a[DIM + k];
        float x2 = (float)a[2 * DIM + k];
        float x3 = (float)a[3 * DIM + k];
        acc[0][0] = fmaf(x0, wv.x, acc[0][0]); acc[0][1] = fmaf(x0, wv.y, acc[0][1]);
        acc[0][2] = fmaf(x0, wv.z, acc[0][2]); acc[0][3] = fmaf(x0, wv.w, acc[0][3]);
        acc[1][0] = fmaf(x1, wv.x, acc[1][0]); acc[1][1] = fmaf(x1, wv.y, acc[1][1]);
        acc[1][2] = fmaf(x1, wv.z, acc[1][2]); acc[1][3] = fmaf(x1, wv.w, acc[1][3]);
        acc[2][0] = fmaf(x2, wv.x, acc[2][0]); acc[2][1] = fmaf(x2, wv.y, acc[2][1]);
        acc[2][2] = fmaf(x2, wv.z, acc[2][2]); acc[2][3] = fmaf(x2, wv.w, acc[2][3]);
        acc[3][0] = fmaf(x3, wv.x, acc[3][0]); acc[3][1] = fmaf(x3, wv.y, acc[3][1]);
        acc[3][2] = fmaf(x3, wv.z, acc[3][2]); acc[3][3] = fmaf(x3, wv.w, acc[3][3]);
    }
#pragma unroll
    for (int r = 0; r < 4; ++r) {
        union { __half2 h[2]; float2 f; } u;
        u.h[0] = __floats2half2_rn(acc[r][0], acc[r][1]);
        u.h[1] = __floats2half2_rn(acc[r][2], acc[r][3]);
        ((float2*)(C + (size_t)(row0 + r) * DIM))[cg] = u.f;
    }
}

// ---------------- CSR gather + fused epilogue (fp16 msg) ------------------
// MODE 0: outF_row = half(relu(agg + bias))
// MODE 1: h = relu(agg + bias); outS[v] = dot(h, wf)
template <int MODE>
__global__ void gather_feat(const __half* __restrict__ msg, const unsigned int* __restrict__ pack,
                            const int* __restrict__ rowptr, const float* __restrict__ bias,
                            const float* __restrict__ wf, __half* __restrict__ outF,
                            float* __restrict__ outS) {
    int gid = blockIdx.x * blockDim.x + threadIdx.x;
    int grp = gid >> 5, lane = gid & 31;
    if (grp >= N_NODES) return;
    int beg = rowptr[grp], end = rowptr[grp + 1];
    float ax = 0.f, ay = 0.f, az = 0.f, aw = 0.f;
    int i = beg;
    for (; i + 1 < end; i += 2) {   // 2 independent gather chains
        unsigned int p0 = pack[i], p1 = pack[i + 1];
        float w0 = __half2float(__ushort_as_half((unsigned short)(p0 & 0xffffu)));
        float w1 = __half2float(__ushort_as_half((unsigned short)(p1 & 0xffffu)));
        float2 q0 = ((const float2*)(msg + (size_t)(p0 >> 16) * DIM))[lane];
        float2 q1 = ((const float2*)(msg + (size_t)(p1 >> 16) * DIM))[lane];
        float2 f;
        f = __half22float2(*(const __half2*)&q0.x); ax = fmaf(w0, f.x, ax); ay = fmaf(w0, f.y, ay);
        f = __half22float2(*(const __half2*)&q0.y); az = fmaf(w0, f.x, az); aw = fmaf(w0, f.y, aw);
        f = __half22float2(*(const __half2*)&q1.x); ax = fmaf(w1, f.x, ax); ay = fmaf(w1, f.y, ay);
        f = __half22float2(*(const __half2*)&q1.y); az = fmaf(w1, f.x, az); aw = fmaf(w1, f.y, aw);
    }
    if (i < end) {
        unsigned int p0 = pack[i];
        float w0 = __half2float(__ushort_as_half((unsigned short)(p0 & 0xffffu)));
        float2 q0 = ((const float2*)(msg + (size_t)(p0 >> 16) * DIM))[lane];
        float2 f;
        f = __half22float2(*(const __half2*)&q0.x); ax = fmaf(w0, f.x, ax); ay = fmaf(w0, f.y, ay);
        f = __half22float2(*(const __half2*)&q0.y); az = fmaf(w0, f.x, az); aw = fmaf(w0, f.y, aw);
    }
    float4 b = ((const float4*)bias)[lane];
    ax = fmaxf(ax + b.x, 0.f);
    ay = fmaxf(ay + b.y, 0.f);
    az = fmaxf(az + b.z, 0.f);
    aw = fmaxf(aw + b.w, 0.f);
    if (MODE == 0) {
        union { __half2 h[2]; float2 f; } u;
        u.h[0] = __floats2half2_rn(ax, ay);
        u.h[1] = __floats2half2_rn(az, aw);
        ((float2*)(outF + (size_t)grp * DIM))[lane] = u.f;
    } else {
        float4 f = ((const float4*)wf)[lane];
        float d = ax * f.x + ay * f.y + az * f.z + aw * f.w;
#pragma unroll
        for (int off = 16; off; off >>= 1) d += __shfl_down(d, off, 32);
        if (lane == 0) outS[grp] = d;
    }
}

// ---------------- fused final aggregation + per-graph readout -------------
// block g: nodes [g*NPG, (g+1)*NPG); out[g] = mean sigmoid(sum_in w*s[src] + bf)
__global__ void final_readout(const float* __restrict__ s, const unsigned int* __restrict__ pack,
                              const int* __restrict__ rowptr, const float* __restrict__ bfp,
                              float* __restrict__ out) {
    __shared__ float red[256];
    int g = blockIdx.x;
    float bf = bfp[0];
    float sum = 0.f;
    for (int n = threadIdx.x; n < NPG; n += blockDim.x) {
        int v = g * NPG + n;
        int beg = rowptr[v], end = rowptr[v + 1];
        float a = 0.f;
        for (int i = beg; i < end; ++i) {
            unsigned int p = pack[i];
            a += __half2float(__ushort_as_half((unsigned short)(p & 0xffffu))) * s[p >> 16];
        }
        a += bf;
        sum += 1.f / (1.f + expf(-a));
    }
    red[threadIdx.x] = sum;
    __syncthreads();
    for (int t = 128; t > 0; t >>= 1) {
        if (threadIdx.x < t) red[threadIdx.x] += red[threadIdx.x + t];
        __syncthreads();
    }
    if (threadIdx.x == 0) out[g] = red[0] / (float)NPG;
}

extern "C" void kernel_launch(void* const* d_in, const int* in_sizes, int n_in,
                              void* d_out, int out_size, void* d_ws, size_t ws_size,
                              hipStream_t stream) {
    const float* X  = (const float*)d_in[0];
    const float* ew = (const float*)d_in[1];
    const float* W1 = (const float*)d_in[2];
    const float* b1 = (const float*)d_in[3];
    const float* W2 = (const float*)d_in[4];
    const float* b2 = (const float*)d_in[5];
    const float* Wf = (const float*)d_in[6];
    const float* bf = (const float*)d_in[7];
    const int* ei   = (const int*)d_in[8];
    const int* src  = ei;
    const int* dst  = ei + NEDGE;

    float* out = (float*)d_out;

    // workspace layout
    char* ws = (char*)d_ws;
    size_t off = 0;
    __half* bufA = (__half*)(ws + off); off += (size_t)N_NODES * DIM * 2;     // 12.8 MB
    __half* bufB = (__half*)(ws + off); off += (size_t)N_NODES * DIM * 2;     // 12.8 MB
    unsigned int* pack = (unsigned int*)(ws + off); off += (size_t)NEDGE * 4; // 3.2 MB
    int* rowptr = (int*)(ws + off);   off += (size_t)(N_NODES + 64) * 4;
    int* cnt    = (int*)(ws + off);   off += (size_t)N_NODES * 4;
    int* cursor = (int*)(ws + off);   off += (size_t)N_NODES * 4;
    int* blkSum = (int*)(ws + off);   off += (size_t)256 * 4;
    float* s_node = (float*)(ws + off); off += (size_t)N_NODES * 4;

    const int TB = 256;
    const int EBLK = (NEDGE + TB - 1) / TB;               // 3125
    const int GATHER_BLK = (N_NODES * 32 + TB - 1) / TB;  // 6250
    const int GEMM_BLK = (N_NODES + 31) / 32;             // 1563

    // ---- CSR build (by dst) ----
    hipMemsetAsync(cnt, 0, (size_t)N_NODES * 4, stream);
    hist_kernel<<<EBLK, TB, 0, stream>>>(dst, cnt, NEDGE);
    scan_phaseA<<<NB_SCAN, TB, 0, stream>>>(cnt, blkSum);
    scan_phaseB<<<1, 256, 0, stream>>>(blkSum, NB_SCAN);
    scan_phaseC<<<NB_SCAN, TB, 0, stream>>>(cnt, blkSum, rowptr, cursor);
    place_kernel<<<EBLK, TB, 0, stream>>>(src, dst, ew, cursor, pack, NEDGE);

    // ---- layer 1: h1 = relu(A(X@W1) + b1) ----
    gemm128<float><<<GEMM_BLK, TB, 0, stream>>>(X, W1, bufA);
    gather_feat<0><<<GATHER_BLK, TB, 0, stream>>>(bufA, pack, rowptr, b1,
                                                  nullptr, bufB, nullptr);
    // ---- layer 2 + Wf dot: s = relu(A(h1@W2) + b2) @ Wf ----
    gemm128<__half><<<GEMM_BLK, TB, 0, stream>>>(bufB, W2, bufA);
    gather_feat<1><<<GATHER_BLK, TB, 0, stream>>>(bufA, pack, rowptr, b2,
                                                  Wf, nullptr, s_node);
    // ---- final aggregation + readout (fused) ----
    final_readout<<<NGRAPH, TB, 0, stream>>>(s_node, pack, rowptr, bf, out);
}

// Round 5
// 207.934 us; speedup vs baseline: 14.8283x; 1.3296x over previous
//
#include <hip/hip_runtime.h>
#include <hip/hip_fp16.h>

#define N_NODES 50000
#define DIM 128
#define NEDGE 800000
#define NGRAPH 100
#define NPG 500      // nodes per graph
#define NBUCKET 250  // dst buckets
#define NPB 200      // nodes per bucket (250*200 == 50000 exactly)
#define BCAP 4096    // padded slots per bucket (mean 3200, sd 56 -> safe)
#define CHUNK 2048   // edges per block in scatter pass
#define EPT (CHUNK / 256)

// ---------------- cursor init: gCur[b] = b*BCAP ----------------
__global__ void init_cursor(int* __restrict__ gCur) {
    int t = threadIdx.x;
    if (t < NBUCKET) gCur[t] = t * BCAP;
}

// ---------------- pass 1: bucket edges by dst/NPB --------------
// Block-private range reservation -> writes are dense ~line-sized runs.
__global__ void bucket_scatter(const int* __restrict__ src, const int* __restrict__ dst,
                               const float* __restrict__ w, int* __restrict__ gCur,
                               uint2* __restrict__ stage, int E) {
    __shared__ int hist[NBUCKET];
    __shared__ int base[NBUCKET];
    for (int i = threadIdx.x; i < NBUCKET; i += 256) hist[i] = 0;
    __syncthreads();
    const int e0 = blockIdx.x * CHUNK;
    int myDst[EPT];
#pragma unroll
    for (int j = 0; j < EPT; ++j) {
        int e = e0 + j * 256 + threadIdx.x;
        int d = (e < E) ? dst[e] : -1;
        myDst[j] = d;
        if (d >= 0) atomicAdd(&hist[d / NPB], 1);
    }
    __syncthreads();
    for (int i = threadIdx.x; i < NBUCKET; i += 256)
        base[i] = atomicAdd(&gCur[i], hist[i]);   // reserve private run
    __syncthreads();
#pragma unroll
    for (int j = 0; j < EPT; ++j) {
        int d = myDst[j];
        if (d >= 0) {
            int e = e0 + j * 256 + threadIdx.x;
            int b = d / NPB;
            int p = atomicAdd(&base[b], 1);
            unsigned short wh = __half_as_ushort(__float2half_rn(w[e]));
            stage[p] = make_uint2(((unsigned)src[e] << 16) | (unsigned)wh,
                                  (unsigned)(d - b * NPB));
        }
    }
}

// ---------------- pass 2: per-bucket local CSR -----------------
// Block b: histogram 200 local nodes, scan, place 4B packs, emit (beg,end).
__global__ void bucket_build(const int* __restrict__ gCur, const uint2* __restrict__ stage,
                             unsigned int* __restrict__ pack, int2* __restrict__ range) {
    __shared__ int lhist[NPB];
    __shared__ int lincl[256];
    __shared__ int lcur[NPB];
    const int b = blockIdx.x;
    const int t = threadIdx.x;
    const int cnt = gCur[b] - b * BCAP;
    for (int i = t; i < NPB; i += 256) lhist[i] = 0;
    __syncthreads();
    unsigned myX[BCAP / 256];
    int myLd[BCAP / 256];
#pragma unroll
    for (int j = 0; j < BCAP / 256; ++j) {
        int i = j * 256 + t;
        if (i < cnt) {
            uint2 r = stage[b * BCAP + i];
            myX[j] = r.x;
            myLd[j] = (int)r.y;
            atomicAdd(&lhist[r.y], 1);
        } else {
            myLd[j] = -1;
        }
    }
    __syncthreads();
    int h = (t < NPB) ? lhist[t] : 0;
    lincl[t] = h;
    __syncthreads();
    for (int off = 1; off < 256; off <<= 1) {
        int v = (t >= off) ? lincl[t - off] : 0;
        __syncthreads();
        lincl[t] += v;
        __syncthreads();
    }
    if (t < NPB) lcur[t] = lincl[t] - h;   // exclusive prefix
    __syncthreads();
#pragma unroll
    for (int j = 0; j < BCAP / 256; ++j) {
        if (myLd[j] >= 0) {
            int p = atomicAdd(&lcur[myLd[j]], 1);
            pack[b * BCAP + p] = myX[j];
        }
    }
    if (t < NPB) {
        int v = b * NPB + t;
        range[v] = make_int2(b * BCAP + lincl[t] - h, b * BCAP + lincl[t]);
    }
}

// ---------------- GEMM: C[n,128] = A[n,128] @ W[128,128], C in fp16 -------
template <typename TIN>
__global__ void gemm128(const TIN* __restrict__ A, const float* __restrict__ W,
                        __half* __restrict__ C) {
    __shared__ float Wl[DIM * DIM];
    for (int i = threadIdx.x; i < DIM * DIM; i += 256) Wl[i] = W[i];
    __syncthreads();
    const int cg = threadIdx.x & 31;
    const int tr = threadIdx.x >> 5;
    const int row0 = blockIdx.x * 32 + tr * 4;
    if (row0 >= N_NODES) return;
    const TIN* a = A + (size_t)row0 * DIM;
    float acc[4][4] = {};
#pragma unroll 4
    for (int k = 0; k < DIM; ++k) {
        float4 wv = *(const float4*)(&Wl[k * DIM + cg * 4]);
        float x0 = (float)a[k];
        float x1 = (float)a[DIM + k];
        float x2 = (float)a[2 * DIM + k];
        float x3 = (float)a[3 * DIM + k];
        acc[0][0] = fmaf(x0, wv.x, acc[0][0]); acc[0][1] = fmaf(x0, wv.y, acc[0][1]);
        acc[0][2] = fmaf(x0, wv.z, acc[0][2]); acc[0][3] = fmaf(x0, wv.w, acc[0][3]);
        acc[1][0] = fmaf(x1, wv.x, acc[1][0]); acc[1][1] = fmaf(x1, wv.y, acc[1][1]);
        acc[1][2] = fmaf(x1, wv.z, acc[1][2]); acc[1][3] = fmaf(x1, wv.w, acc[1][3]);
        acc[2][0] = fmaf(x2, wv.x, acc[2][0]); acc[2][1] = fmaf(x2, wv.y, acc[2][1]);
        acc[2][2] = fmaf(x2, wv.z, acc[2][2]); acc[2][3] = fmaf(x2, wv.w, acc[2][3]);
        acc[3][0] = fmaf(x3, wv.x, acc[3][0]); acc[3][1] = fmaf(x3, wv.y, acc[3][1]);
        acc[3][2] = fmaf(x3, wv.z, acc[3][2]); acc[3][3] = fmaf(x3, wv.w, acc[3][3]);
    }
#pragma unroll
    for (int r = 0; r < 4; ++r) {
        union { __half2 h[2]; float2 f; } u;
        u.h[0] = __floats2half2_rn(acc[r][0], acc[r][1]);
        u.h[1] = __floats2half2_rn(acc[r][2], acc[r][3]);
        ((float2*)(C + (size_t)(row0 + r) * DIM))[cg] = u.f;
    }
}

// ---------------- CSR gather + fused epilogue (fp16 msg) ------------------
// MODE 0: outF_row = half(relu(agg + bias))
// MODE 1: h = relu(agg + bias); outS[v] = dot(h, wf)
template <int MODE>
__global__ void gather_feat(const __half* __restrict__ msg, const unsigned int* __restrict__ pack,
                            const int2* __restrict__ range, const float* __restrict__ bias,
                            const float* __restrict__ wf, __half* __restrict__ outF,
                            float* __restrict__ outS) {
    int gid = blockIdx.x * blockDim.x + threadIdx.x;
    int grp = gid >> 5, lane = gid & 31;
    if (grp >= N_NODES) return;
    int2 r = range[grp];
    int beg = r.x, end = r.y;
    float ax = 0.f, ay = 0.f, az = 0.f, aw = 0.f;
    int i = beg;
    for (; i + 1 < end; i += 2) {
        unsigned int p0 = pack[i], p1 = pack[i + 1];
        float w0 = __half2float(__ushort_as_half((unsigned short)(p0 & 0xffffu)));
        float w1 = __half2float(__ushort_as_half((unsigned short)(p1 & 0xffffu)));
        float2 q0 = ((const float2*)(msg + (size_t)(p0 >> 16) * DIM))[lane];
        float2 q1 = ((const float2*)(msg + (size_t)(p1 >> 16) * DIM))[lane];
        float2 f;
        f = __half22float2(*(const __half2*)&q0.x); ax = fmaf(w0, f.x, ax); ay = fmaf(w0, f.y, ay);
        f = __half22float2(*(const __half2*)&q0.y); az = fmaf(w0, f.x, az); aw = fmaf(w0, f.y, aw);
        f = __half22float2(*(const __half2*)&q1.x); ax = fmaf(w1, f.x, ax); ay = fmaf(w1, f.y, ay);
        f = __half22float2(*(const __half2*)&q1.y); az = fmaf(w1, f.x, az); aw = fmaf(w1, f.y, aw);
    }
    if (i < end) {
        unsigned int p0 = pack[i];
        float w0 = __half2float(__ushort_as_half((unsigned short)(p0 & 0xffffu)));
        float2 q0 = ((const float2*)(msg + (size_t)(p0 >> 16) * DIM))[lane];
        float2 f;
        f = __half22float2(*(const __half2*)&q0.x); ax = fmaf(w0, f.x, ax); ay = fmaf(w0, f.y, ay);
        f = __half22float2(*(const __half2*)&q0.y); az = fmaf(w0, f.x, az); aw = fmaf(w0, f.y, aw);
    }
    float4 b = ((const float4*)bias)[lane];
    ax = fmaxf(ax + b.x, 0.f);
    ay = fmaxf(ay + b.y, 0.f);
    az = fmaxf(az + b.z, 0.f);
    aw = fmaxf(aw + b.w, 0.f);
    if (MODE == 0) {
        union { __half2 h[2]; float2 f; } u;
        u.h[0] = __floats2half2_rn(ax, ay);
        u.h[1] = __floats2half2_rn(az, aw);
        ((float2*)(outF + (size_t)grp * DIM))[lane] = u.f;
    } else {
        float4 f = ((const float4*)wf)[lane];
        float d = ax * f.x + ay * f.y + az * f.z + aw * f.w;
#pragma unroll
        for (int off = 16; off; off >>= 1) d += __shfl_down(d, off, 32);
        if (lane == 0) outS[grp] = d;
    }
}

// ---------------- fused final aggregation + per-graph readout -------------
__global__ void final_readout(const float* __restrict__ s, const unsigned int* __restrict__ pack,
                              const int2* __restrict__ range, const float* __restrict__ bfp,
                              float* __restrict__ out) {
    __shared__ float red[256];
    int g = blockIdx.x;
    float bf = bfp[0];
    float sum = 0.f;
    for (int n = threadIdx.x; n < NPG; n += blockDim.x) {
        int v = g * NPG + n;
        int2 r = range[v];
        float a = 0.f;
        for (int i = r.x; i < r.y; ++i) {
            unsigned int p = pack[i];
            a += __half2float(__ushort_as_half((unsigned short)(p & 0xffffu))) * s[p >> 16];
        }
        a += bf;
        sum += 1.f / (1.f + expf(-a));
    }
    red[threadIdx.x] = sum;
    __syncthreads();
    for (int t = 128; t > 0; t >>= 1) {
        if (threadIdx.x < t) red[threadIdx.x] += red[threadIdx.x + t];
        __syncthreads();
    }
    if (threadIdx.x == 0) out[g] = red[0] / (float)NPG;
}

extern "C" void kernel_launch(void* const* d_in, const int* in_sizes, int n_in,
                              void* d_out, int out_size, void* d_ws, size_t ws_size,
                              hipStream_t stream) {
    const float* X  = (const float*)d_in[0];
    const float* ew = (const float*)d_in[1];
    const float* W1 = (const float*)d_in[2];
    const float* b1 = (const float*)d_in[3];
    const float* W2 = (const float*)d_in[4];
    const float* b2 = (const float*)d_in[5];
    const float* Wf = (const float*)d_in[6];
    const float* bf = (const float*)d_in[7];
    const int* ei   = (const int*)d_in[8];
    const int* src  = ei;
    const int* dst  = ei + NEDGE;

    float* out = (float*)d_out;

    // workspace layout
    char* ws = (char*)d_ws;
    size_t off = 0;
    __half* bufA = (__half*)(ws + off); off += (size_t)N_NODES * DIM * 2;       // 12.8 MB
    __half* bufB = (__half*)(ws + off); off += (size_t)N_NODES * DIM * 2;       // 12.8 MB
    uint2* stage = (uint2*)(ws + off);  off += (size_t)NBUCKET * BCAP * 8;      // 8 MB
    unsigned int* pack = (unsigned int*)(ws + off); off += (size_t)NBUCKET * BCAP * 4; // 4 MB
    int2* range = (int2*)(ws + off);    off += (size_t)N_NODES * 8;             // 400 KB
    int* gCur   = (int*)(ws + off);     off += (size_t)256 * 4;
    float* s_node = (float*)(ws + off); off += (size_t)N_NODES * 4;

    const int TB = 256;
    const int SCAT_BLK = (NEDGE + CHUNK - 1) / CHUNK;     // 391
    const int GATHER_BLK = (N_NODES * 32 + TB - 1) / TB;  // 6250
    const int GEMM_BLK = (N_NODES + 31) / 32;             // 1563

    // ---- CSR build (bucketed counting sort, no random line scatter) ----
    init_cursor<<<1, 256, 0, stream>>>(gCur);
    bucket_scatter<<<SCAT_BLK, TB, 0, stream>>>(src, dst, ew, gCur, stage, NEDGE);
    bucket_build<<<NBUCKET, TB, 0, stream>>>(gCur, stage, pack, range);

    // ---- layer 1: h1 = relu(A(X@W1) + b1) ----
    gemm128<float><<<GEMM_BLK, TB, 0, stream>>>(X, W1, bufA);
    gather_feat<0><<<GATHER_BLK, TB, 0, stream>>>(bufA, pack, range, b1,
                                                  nullptr, bufB, nullptr);
    // ---- layer 2 + Wf dot: s = relu(A(h1@W2) + b2) @ Wf ----
    gemm128<__half><<<GEMM_BLK, TB, 0, stream>>>(bufB, W2, bufA);
    gather_feat<1><<<GATHER_BLK, TB, 0, stream>>>(bufA, pack, range, b2,
                                                  Wf, nullptr, s_node);
    // ---- final aggregation + readout (fused) ----
    final_readout<<<NGRAPH, TB, 0, stream>>>(s_node, pack, range, bf, out);
}

// Round 6
// 175.049 us; speedup vs baseline: 17.6140x; 1.1879x over previous
//
#include <hip/hip_runtime.h>
#include <hip/hip_fp16.h>

#define N_NODES 50000
#define DIM 128
#define NEDGE 800000
#define NGRAPH 100
#define NPG 500      // nodes per graph
#define NBUCKET 250  // dst buckets
#define NPB 200      // nodes per bucket (250*200 == 50000 exactly)
#define BCAP 4096    // padded slots per bucket (mean 3200, sd 56 -> safe)
#define CHUNK 2048   // edges per block in scatter pass
#define EPT (CHUNK / 256)

typedef _Float16 f16x8 __attribute__((ext_vector_type(8)));
typedef float f32x4 __attribute__((ext_vector_type(4)));

// ---------------- cursor init: gCur[b] = b*BCAP ----------------
__global__ void init_cursor(int* __restrict__ gCur) {
    int t = threadIdx.x;
    if (t < NBUCKET) gCur[t] = t * BCAP;
}

// ---------------- pass 1: bucket edges by dst/NPB --------------
__global__ void bucket_scatter(const int* __restrict__ src, const int* __restrict__ dst,
                               const float* __restrict__ w, int* __restrict__ gCur,
                               uint2* __restrict__ stage, int E) {
    __shared__ int hist[NBUCKET];
    __shared__ int base[NBUCKET];
    for (int i = threadIdx.x; i < NBUCKET; i += 256) hist[i] = 0;
    __syncthreads();
    const int e0 = blockIdx.x * CHUNK;
    int myDst[EPT];
#pragma unroll
    for (int j = 0; j < EPT; ++j) {
        int e = e0 + j * 256 + threadIdx.x;
        int d = (e < E) ? dst[e] : -1;
        myDst[j] = d;
        if (d >= 0) atomicAdd(&hist[d / NPB], 1);
    }
    __syncthreads();
    for (int i = threadIdx.x; i < NBUCKET; i += 256)
        base[i] = atomicAdd(&gCur[i], hist[i]);   // reserve private run
    __syncthreads();
#pragma unroll
    for (int j = 0; j < EPT; ++j) {
        int d = myDst[j];
        if (d >= 0) {
            int e = e0 + j * 256 + threadIdx.x;
            int b = d / NPB;
            int p = atomicAdd(&base[b], 1);
            unsigned short wh = __half_as_ushort(__float2half_rn(w[e]));
            stage[p] = make_uint2(((unsigned)src[e] << 16) | (unsigned)wh,
                                  (unsigned)(d - b * NPB));
        }
    }
}

// ---------------- pass 2: per-bucket local CSR -----------------
__global__ void bucket_build(const int* __restrict__ gCur, const uint2* __restrict__ stage,
                             unsigned int* __restrict__ pack, int2* __restrict__ range) {
    __shared__ int lhist[NPB];
    __shared__ int lincl[256];
    __shared__ int lcur[NPB];
    const int b = blockIdx.x;
    const int t = threadIdx.x;
    const int cnt = gCur[b] - b * BCAP;
    for (int i = t; i < NPB; i += 256) lhist[i] = 0;
    __syncthreads();
    unsigned myX[BCAP / 256];
    int myLd[BCAP / 256];
#pragma unroll
    for (int j = 0; j < BCAP / 256; ++j) {
        int i = j * 256 + t;
        if (i < cnt) {
            uint2 r = stage[b * BCAP + i];
            myX[j] = r.x;
            myLd[j] = (int)r.y;
            atomicAdd(&lhist[r.y], 1);
        } else {
            myLd[j] = -1;
        }
    }
    __syncthreads();
    int h = (t < NPB) ? lhist[t] : 0;
    lincl[t] = h;
    __syncthreads();
    for (int off = 1; off < 256; off <<= 1) {
        int v = (t >= off) ? lincl[t - off] : 0;
        __syncthreads();
        lincl[t] += v;
        __syncthreads();
    }
    if (t < NPB) lcur[t] = lincl[t] - h;   // exclusive prefix
    __syncthreads();
#pragma unroll
    for (int j = 0; j < BCAP / 256; ++j) {
        if (myLd[j] >= 0) {
            int p = atomicAdd(&lcur[myLd[j]], 1);
            pack[b * BCAP + p] = myX[j];
        }
    }
    if (t < NPB) {
        int v = b * NPB + t;
        range[v] = make_int2(b * BCAP + lincl[t] - h, b * BCAP + lincl[t]);
    }
}

// ---------------- MFMA GEMM: C[n,128] = A[n,128] @ W[128,128] -> fp16 -----
// 4 waves/block; wave computes 16 rows x 128 cols via mfma_f32_16x16x32_f16.
// A-frag: row = lane&15, k = (lane>>4)*8 + j.  B-frag: col = lane&15, same k.
// C/D:    col = lane&15, row = (lane>>4)*4 + reg.
__device__ inline f16x8 load_afrag_f32(const float* a) {
    float4 u0 = *(const float4*)a;
    float4 u1 = *(const float4*)(a + 4);
    f16x8 r;
    r[0] = (_Float16)u0.x; r[1] = (_Float16)u0.y; r[2] = (_Float16)u0.z; r[3] = (_Float16)u0.w;
    r[4] = (_Float16)u1.x; r[5] = (_Float16)u1.y; r[6] = (_Float16)u1.z; r[7] = (_Float16)u1.w;
    return r;
}
__device__ inline f16x8 load_afrag_f16(const __half* a) {
    union { float4 f; f16x8 h; } u;
    u.f = *(const float4*)a;
    return u.h;
}

template <typename TIN>
__global__ void gemm_mfma(const TIN* __restrict__ A, const float* __restrict__ W,
                          __half* __restrict__ C) {
    // fragW[nt][kt][lane][j] : B-fragment for N-tile nt, K-tile kt
    __shared__ __align__(16) _Float16 fragW[8 * 4 * 64 * 8];   // 32 KB
    const int tid = threadIdx.x;
    for (int idx = tid; idx < 8 * 4 * 64 * 8; idx += 256) {
        int j = idx & 7, l = (idx >> 3) & 63, kt = (idx >> 9) & 3, nt = idx >> 11;
        int k = kt * 32 + ((l >> 4) << 3) + j;
        int col = (nt << 4) + (l & 15);
        fragW[idx] = (_Float16)W[k * DIM + col];
    }
    __syncthreads();
    const int lane = tid & 63;
    const int wid = tid >> 6;
    const int row0 = blockIdx.x * 64 + wid * 16;
    if (row0 >= N_NODES) return;   // no syncs below: safe for tail waves
    const int arow = row0 + (lane & 15);
    const int koff = (lane >> 4) << 3;
    f32x4 acc[8] = {};
#pragma unroll
    for (int kt = 0; kt < 4; ++kt) {
        f16x8 a;
        const TIN* ap = A + (size_t)arow * DIM + kt * 32 + koff;
        if constexpr (sizeof(TIN) == 4) a = load_afrag_f32((const float*)ap);
        else                            a = load_afrag_f16((const __half*)ap);
#pragma unroll
        for (int nt = 0; nt < 8; ++nt) {
            f16x8 b = *(const f16x8*)&fragW[(((nt << 2) | kt) << 9) | (lane << 3)];
            acc[nt] = __builtin_amdgcn_mfma_f32_16x16x32_f16(a, b, acc[nt], 0, 0, 0);
        }
    }
    const int crow = row0 + ((lane >> 4) << 2);
    const int ccol = lane & 15;
#pragma unroll
    for (int nt = 0; nt < 8; ++nt) {
#pragma unroll
        for (int r = 0; r < 4; ++r) {
            C[(size_t)(crow + r) * DIM + (nt << 4) + ccol] = __float2half_rn(acc[nt][r]);
        }
    }
}

// ---------------- CSR gather + fused epilogue (fp16 msg) ------------------
// MODE 0: outF_row = half(relu(agg + bias))
// MODE 1: h = relu(agg + bias); outS[v] = dot(h, wf)
template <int MODE>
__global__ void gather_feat(const __half* __restrict__ msg, const unsigned int* __restrict__ pack,
                            const int2* __restrict__ range, const float* __restrict__ bias,
                            const float* __restrict__ wf, __half* __restrict__ outF,
                            float* __restrict__ outS) {
    int gid = blockIdx.x * blockDim.x + threadIdx.x;
    int grp = gid >> 5, lane = gid & 31;
    if (grp >= N_NODES) return;
    int2 r = range[grp];
    int beg = r.x, end = r.y;
    float ax = 0.f, ay = 0.f, az = 0.f, aw = 0.f;
    int i = beg;
    for (; i + 1 < end; i += 2) {
        unsigned int p0 = pack[i], p1 = pack[i + 1];
        float w0 = __half2float(__ushort_as_half((unsigned short)(p0 & 0xffffu)));
        float w1 = __half2float(__ushort_as_half((unsigned short)(p1 & 0xffffu)));
        float2 q0 = ((const float2*)(msg + (size_t)(p0 >> 16) * DIM))[lane];
        float2 q1 = ((const float2*)(msg + (size_t)(p1 >> 16) * DIM))[lane];
        float2 f;
        f = __half22float2(*(const __half2*)&q0.x); ax = fmaf(w0, f.x, ax); ay = fmaf(w0, f.y, ay);
        f = __half22float2(*(const __half2*)&q0.y); az = fmaf(w0, f.x, az); aw = fmaf(w0, f.y, aw);
        f = __half22float2(*(const __half2*)&q1.x); ax = fmaf(w1, f.x, ax); ay = fmaf(w1, f.y, ay);
        f = __half22float2(*(const __half2*)&q1.y); az = fmaf(w1, f.x, az); aw = fmaf(w1, f.y, aw);
    }
    if (i < end) {
        unsigned int p0 = pack[i];
        float w0 = __half2float(__ushort_as_half((unsigned short)(p0 & 0xffffu)));
        float2 q0 = ((const float2*)(msg + (size_t)(p0 >> 16) * DIM))[lane];
        float2 f;
        f = __half22float2(*(const __half2*)&q0.x); ax = fmaf(w0, f.x, ax); ay = fmaf(w0, f.y, ay);
        f = __half22float2(*(const __half2*)&q0.y); az = fmaf(w0, f.x, az); aw = fmaf(w0, f.y, aw);
    }
    float4 b = ((const float4*)bias)[lane];
    ax = fmaxf(ax + b.x, 0.f);
    ay = fmaxf(ay + b.y, 0.f);
    az = fmaxf(az + b.z, 0.f);
    aw = fmaxf(aw + b.w, 0.f);
    if (MODE == 0) {
        union { __half2 h[2]; float2 f; } u;
        u.h[0] = __floats2half2_rn(ax, ay);
        u.h[1] = __floats2half2_rn(az, aw);
        ((float2*)(outF + (size_t)grp * DIM))[lane] = u.f;
    } else {
        float4 f = ((const float4*)wf)[lane];
        float d = ax * f.x + ay * f.y + az * f.z + aw * f.w;
#pragma unroll
        for (int off = 16; off; off >>= 1) d += __shfl_down(d, off, 32);
        if (lane == 0) outS[grp] = d;
    }
}

// ---------------- fused final aggregation + per-graph readout -------------
__global__ void final_readout(const float* __restrict__ s, const unsigned int* __restrict__ pack,
                              const int2* __restrict__ range, const float* __restrict__ bfp,
                              float* __restrict__ out) {
    __shared__ float red[256];
    int g = blockIdx.x;
    float bf = bfp[0];
    float sum = 0.f;
    for (int n = threadIdx.x; n < NPG; n += blockDim.x) {
        int v = g * NPG + n;
        int2 r = range[v];
        float a = 0.f;
        for (int i = r.x; i < r.y; ++i) {
            unsigned int p = pack[i];
            a += __half2float(__ushort_as_half((unsigned short)(p & 0xffffu))) * s[p >> 16];
        }
        a += bf;
        sum += 1.f / (1.f + expf(-a));
    }
    red[threadIdx.x] = sum;
    __syncthreads();
    for (int t = 128; t > 0; t >>= 1) {
        if (threadIdx.x < t) red[threadIdx.x] += red[threadIdx.x + t];
        __syncthreads();
    }
    if (threadIdx.x == 0) out[g] = red[0] / (float)NPG;
}

extern "C" void kernel_launch(void* const* d_in, const int* in_sizes, int n_in,
                              void* d_out, int out_size, void* d_ws, size_t ws_size,
                              hipStream_t stream) {
    const float* X  = (const float*)d_in[0];
    const float* ew = (const float*)d_in[1];
    const float* W1 = (const float*)d_in[2];
    const float* b1 = (const float*)d_in[3];
    const float* W2 = (const float*)d_in[4];
    const float* b2 = (const float*)d_in[5];
    const float* Wf = (const float*)d_in[6];
    const float* bf = (const float*)d_in[7];
    const int* ei   = (const int*)d_in[8];
    const int* src  = ei;
    const int* dst  = ei + NEDGE;

    float* out = (float*)d_out;

    // workspace layout
    char* ws = (char*)d_ws;
    size_t off = 0;
    __half* bufA = (__half*)(ws + off); off += (size_t)N_NODES * DIM * 2;       // 12.8 MB
    __half* bufB = (__half*)(ws + off); off += (size_t)N_NODES * DIM * 2;       // 12.8 MB
    uint2* stage = (uint2*)(ws + off);  off += (size_t)NBUCKET * BCAP * 8;      // 8 MB
    unsigned int* pack = (unsigned int*)(ws + off); off += (size_t)NBUCKET * BCAP * 4; // 4 MB
    int2* range = (int2*)(ws + off);    off += (size_t)N_NODES * 8;             // 400 KB
    int* gCur   = (int*)(ws + off);     off += (size_t)256 * 4;
    float* s_node = (float*)(ws + off); off += (size_t)N_NODES * 4;

    const int TB = 256;
    const int SCAT_BLK = (NEDGE + CHUNK - 1) / CHUNK;     // 391
    const int GATHER_BLK = (N_NODES * 32 + TB - 1) / TB;  // 6250
    const int MFMA_BLK = (N_NODES + 63) / 64;             // 782

    // ---- CSR build (bucketed counting sort) ----
    init_cursor<<<1, 256, 0, stream>>>(gCur);
    bucket_scatter<<<SCAT_BLK, TB, 0, stream>>>(src, dst, ew, gCur, stage, NEDGE);
    bucket_build<<<NBUCKET, TB, 0, stream>>>(gCur, stage, pack, range);

    // ---- layer 1: h1 = relu(A(X@W1) + b1) ----
    gemm_mfma<float><<<MFMA_BLK, TB, 0, stream>>>(X, W1, bufA);
    gather_feat<0><<<GATHER_BLK, TB, 0, stream>>>(bufA, pack, range, b1,
                                                  nullptr, bufB, nullptr);
    // ---- layer 2 + Wf dot: s = relu(A(h1@W2) + b2) @ Wf ----
    gemm_mfma<__half><<<MFMA_BLK, TB, 0, stream>>>(bufB, W2, bufA);
    gather_feat<1><<<GATHER_BLK, TB, 0, stream>>>(bufA, pack, range, b2,
                                                  Wf, nullptr, s_node);
    // ---- final aggregation + readout (fused) ----
    final_readout<<<NGRAPH, TB, 0, stream>>>(s_node, pack, range, bf, out);
}

// Round 7
// 134.670 us; speedup vs baseline: 22.8954x; 1.2998x over previous
//
#include <hip/hip_runtime.h>
#include <hip/hip_fp16.h>

#define N_NODES 50000
#define DIM 128
#define NEDGE 800000
#define NGRAPH 100
#define NPG 500      // nodes per graph
#define NBUCKET 250  // dst buckets
#define NPB 200      // nodes per bucket (250*200 == 50000 exactly)
#define BCAP 4096    // padded slots per bucket (mean 3200, sd 56 -> safe)
#define CHUNK 2048   // edges per block in scatter pass
#define EPT (CHUNK / 256)

typedef _Float16 f16x8 __attribute__((ext_vector_type(8)));
typedef float f32x4 __attribute__((ext_vector_type(4)));

// ---------------- prep: cursor init + pre-swizzled fp16 W-fragments -------
// blocks 0..63: fragW1, 64..127: fragW2, 128: gCur init.
// frag layout idx = ((nt*4+kt)*64+lane)*8+j ; value W[k*DIM+col],
// k = kt*32+(lane>>4)*8+j, col = nt*16+(lane&15)  (mfma_f32_16x16x32_f16).
__global__ void prep(const float* __restrict__ W1, const float* __restrict__ W2,
                     _Float16* __restrict__ fragW1, _Float16* __restrict__ fragW2,
                     int* __restrict__ gCur) {
    const int b = blockIdx.x;
    if (b == 128) {
        int t = threadIdx.x;
        if (t < NBUCKET) gCur[t] = t * BCAP;
        return;
    }
    const float* W = (b < 64) ? W1 : W2;
    _Float16* F = (b < 64) ? fragW1 : fragW2;
    int idx = (b & 63) * 256 + threadIdx.x;   // 0..16383
    int j = idx & 7, l = (idx >> 3) & 63, kt = (idx >> 9) & 3, nt = idx >> 11;
    int k = kt * 32 + ((l >> 4) << 3) + j;
    int col = (nt << 4) + (l & 15);
    F[idx] = (_Float16)W[k * DIM + col];
}

// ---------------- pass 1: bucket edges by dst/NPB --------------
__global__ void bucket_scatter(const int* __restrict__ src, const int* __restrict__ dst,
                               const float* __restrict__ w, int* __restrict__ gCur,
                               uint2* __restrict__ stage, int E) {
    __shared__ int hist[NBUCKET];
    __shared__ int base[NBUCKET];
    for (int i = threadIdx.x; i < NBUCKET; i += 256) hist[i] = 0;
    __syncthreads();
    const int e0 = blockIdx.x * CHUNK;
    int myDst[EPT];
#pragma unroll
    for (int j = 0; j < EPT; ++j) {
        int e = e0 + j * 256 + threadIdx.x;
        int d = (e < E) ? dst[e] : -1;
        myDst[j] = d;
        if (d >= 0) atomicAdd(&hist[d / NPB], 1);
    }
    __syncthreads();
    for (int i = threadIdx.x; i < NBUCKET; i += 256)
        base[i] = atomicAdd(&gCur[i], hist[i]);   // reserve private run
    __syncthreads();
#pragma unroll
    for (int j = 0; j < EPT; ++j) {
        int d = myDst[j];
        if (d >= 0) {
            int e = e0 + j * 256 + threadIdx.x;
            int b = d / NPB;
            int p = atomicAdd(&base[b], 1);
            unsigned short wh = __half_as_ushort(__float2half_rn(w[e]));
            stage[p] = make_uint2(((unsigned)src[e] << 16) | (unsigned)wh,
                                  (unsigned)(d - b * NPB));
        }
    }
}

// ---------------- pass 2: per-bucket local CSR -----------------
__global__ void bucket_build(const int* __restrict__ gCur, const uint2* __restrict__ stage,
                             unsigned int* __restrict__ pack, int2* __restrict__ range) {
    __shared__ int lhist[NPB];
    __shared__ int lincl[256];
    __shared__ int lcur[NPB];
    const int b = blockIdx.x;
    const int t = threadIdx.x;
    const int cnt = gCur[b] - b * BCAP;
    for (int i = t; i < NPB; i += 256) lhist[i] = 0;
    __syncthreads();
    unsigned myX[BCAP / 256];
    int myLd[BCAP / 256];
#pragma unroll
    for (int j = 0; j < BCAP / 256; ++j) {
        int i = j * 256 + t;
        if (i < cnt) {
            uint2 r = stage[b * BCAP + i];
            myX[j] = r.x;
            myLd[j] = (int)r.y;
            atomicAdd(&lhist[r.y], 1);
        } else {
            myLd[j] = -1;
        }
    }
    __syncthreads();
    int h = (t < NPB) ? lhist[t] : 0;
    lincl[t] = h;
    __syncthreads();
    for (int off = 1; off < 256; off <<= 1) {
        int v = (t >= off) ? lincl[t - off] : 0;
        __syncthreads();
        lincl[t] += v;
        __syncthreads();
    }
    if (t < NPB) lcur[t] = lincl[t] - h;   // exclusive prefix
    __syncthreads();
#pragma unroll
    for (int j = 0; j < BCAP / 256; ++j) {
        if (myLd[j] >= 0) {
            int p = atomicAdd(&lcur[myLd[j]], 1);
            pack[b * BCAP + p] = myX[j];
        }
    }
    if (t < NPB) {
        int v = b * NPB + t;
        range[v] = make_int2(b * BCAP + lincl[t] - h, b * BCAP + lincl[t]);
    }
}

// ---------------- MFMA GEMM: C[n,128] = A[n,128] @ W[128,128] -> fp16 -----
// 8 waves/block x 16 rows; pre-swizzled fragments copied global->LDS.
__device__ inline f16x8 load_afrag_f32(const float* a) {
    float4 u0 = *(const float4*)a;
    float4 u1 = *(const float4*)(a + 4);
    f16x8 r;
    r[0] = (_Float16)u0.x; r[1] = (_Float16)u0.y; r[2] = (_Float16)u0.z; r[3] = (_Float16)u0.w;
    r[4] = (_Float16)u1.x; r[5] = (_Float16)u1.y; r[6] = (_Float16)u1.z; r[7] = (_Float16)u1.w;
    return r;
}
__device__ inline f16x8 load_afrag_f16(const __half* a) {
    union { float4 f; f16x8 h; } u;
    u.f = *(const float4*)a;
    return u.h;
}

template <typename TIN>
__global__ __launch_bounds__(512) void gemm_mfma(const TIN* __restrict__ A,
                                                 const _Float16* __restrict__ fragWg,
                                                 __half* __restrict__ C) {
    __shared__ __align__(16) _Float16 fragW[16384];   // 32 KB
    const int tid = threadIdx.x;
    for (int i = tid; i < 2048; i += 512)
        ((uint4*)fragW)[i] = ((const uint4*)fragWg)[i];
    __syncthreads();
    const int lane = tid & 63;
    const int wid = tid >> 6;
    const int row0 = blockIdx.x * 128 + wid * 16;
    if (row0 >= N_NODES) return;   // after sync: safe for tail waves
    const int arow = row0 + (lane & 15);
    const int koff = (lane >> 4) << 3;
    f32x4 acc[8] = {};
#pragma unroll
    for (int kt = 0; kt < 4; ++kt) {
        f16x8 a;
        const TIN* ap = A + (size_t)arow * DIM + kt * 32 + koff;
        if constexpr (sizeof(TIN) == 4) a = load_afrag_f32((const float*)ap);
        else                            a = load_afrag_f16((const __half*)ap);
#pragma unroll
        for (int nt = 0; nt < 8; ++nt) {
            f16x8 b = *(const f16x8*)&fragW[(((nt << 2) | kt) << 9) | (lane << 3)];
            acc[nt] = __builtin_amdgcn_mfma_f32_16x16x32_f16(a, b, acc[nt], 0, 0, 0);
        }
    }
    const int crow = row0 + ((lane >> 4) << 2);
    const int ccol = lane & 15;
#pragma unroll
    for (int nt = 0; nt < 8; ++nt) {
#pragma unroll
        for (int r = 0; r < 4; ++r) {
            C[(size_t)(crow + r) * DIM + (nt << 4) + ccol] = __float2half_rn(acc[nt][r]);
        }
    }
}

// ---------------- CSR gather + fused epilogue (fp16 msg) ------------------
// 16-lane group per node, float4 (16 B) per lane, 2-deep unroll.
// MODE 0: outF_row = half(relu(agg + bias))
// MODE 1: h = relu(agg + bias); outS[v] = dot(h, wf)
template <int MODE>
__global__ void gather_feat(const __half* __restrict__ msg, const unsigned int* __restrict__ pack,
                            const int2* __restrict__ range, const float* __restrict__ bias,
                            const float* __restrict__ wf, __half* __restrict__ outF,
                            float* __restrict__ outS) {
    int gid = blockIdx.x * blockDim.x + threadIdx.x;
    int grp = gid >> 4, lane = gid & 15;
    if (grp >= N_NODES) return;
    int2 r = range[grp];
    int beg = r.x, end = r.y;
    float acc[8] = {};
    int i = beg;
    for (; i + 1 < end; i += 2) {
        unsigned p0 = pack[i], p1 = pack[i + 1];
        float w0 = __half2float(__ushort_as_half((unsigned short)(p0 & 0xffffu)));
        float w1 = __half2float(__ushort_as_half((unsigned short)(p1 & 0xffffu)));
        float4 q0 = ((const float4*)(msg + (size_t)(p0 >> 16) * DIM))[lane];
        float4 q1 = ((const float4*)(msg + (size_t)(p1 >> 16) * DIM))[lane];
        float2 f;
        f = __half22float2(*(const __half2*)&q0.x); acc[0] = fmaf(w0, f.x, acc[0]); acc[1] = fmaf(w0, f.y, acc[1]);
        f = __half22float2(*(const __half2*)&q0.y); acc[2] = fmaf(w0, f.x, acc[2]); acc[3] = fmaf(w0, f.y, acc[3]);
        f = __half22float2(*(const __half2*)&q0.z); acc[4] = fmaf(w0, f.x, acc[4]); acc[5] = fmaf(w0, f.y, acc[5]);
        f = __half22float2(*(const __half2*)&q0.w); acc[6] = fmaf(w0, f.x, acc[6]); acc[7] = fmaf(w0, f.y, acc[7]);
        f = __half22float2(*(const __half2*)&q1.x); acc[0] = fmaf(w1, f.x, acc[0]); acc[1] = fmaf(w1, f.y, acc[1]);
        f = __half22float2(*(const __half2*)&q1.y); acc[2] = fmaf(w1, f.x, acc[2]); acc[3] = fmaf(w1, f.y, acc[3]);
        f = __half22float2(*(const __half2*)&q1.z); acc[4] = fmaf(w1, f.x, acc[4]); acc[5] = fmaf(w1, f.y, acc[5]);
        f = __half22float2(*(const __half2*)&q1.w); acc[6] = fmaf(w1, f.x, acc[6]); acc[7] = fmaf(w1, f.y, acc[7]);
    }
    if (i < end) {
        unsigned p0 = pack[i];
        float w0 = __half2float(__ushort_as_half((unsigned short)(p0 & 0xffffu)));
        float4 q0 = ((const float4*)(msg + (size_t)(p0 >> 16) * DIM))[lane];
        float2 f;
        f = __half22float2(*(const __half2*)&q0.x); acc[0] = fmaf(w0, f.x, acc[0]); acc[1] = fmaf(w0, f.y, acc[1]);
        f = __half22float2(*(const __half2*)&q0.y); acc[2] = fmaf(w0, f.x, acc[2]); acc[3] = fmaf(w0, f.y, acc[3]);
        f = __half22float2(*(const __half2*)&q0.z); acc[4] = fmaf(w0, f.x, acc[4]); acc[5] = fmaf(w0, f.y, acc[5]);
        f = __half22float2(*(const __half2*)&q0.w); acc[6] = fmaf(w0, f.x, acc[6]); acc[7] = fmaf(w0, f.y, acc[7]);
    }
    float4 b0 = ((const float4*)bias)[2 * lane];
    float4 b1 = ((const float4*)bias)[2 * lane + 1];
    acc[0] = fmaxf(acc[0] + b0.x, 0.f); acc[1] = fmaxf(acc[1] + b0.y, 0.f);
    acc[2] = fmaxf(acc[2] + b0.z, 0.f); acc[3] = fmaxf(acc[3] + b0.w, 0.f);
    acc[4] = fmaxf(acc[4] + b1.x, 0.f); acc[5] = fmaxf(acc[5] + b1.y, 0.f);
    acc[6] = fmaxf(acc[6] + b1.z, 0.f); acc[7] = fmaxf(acc[7] + b1.w, 0.f);
    if (MODE == 0) {
        union { __half2 h[4]; float4 f; } u;
        u.h[0] = __floats2half2_rn(acc[0], acc[1]);
        u.h[1] = __floats2half2_rn(acc[2], acc[3]);
        u.h[2] = __floats2half2_rn(acc[4], acc[5]);
        u.h[3] = __floats2half2_rn(acc[6], acc[7]);
        ((float4*)(outF + (size_t)grp * DIM))[lane] = u.f;
    } else {
        float4 f0 = ((const float4*)wf)[2 * lane];
        float4 f1 = ((const float4*)wf)[2 * lane + 1];
        float d = acc[0] * f0.x + acc[1] * f0.y + acc[2] * f0.z + acc[3] * f0.w
                + acc[4] * f1.x + acc[5] * f1.y + acc[6] * f1.z + acc[7] * f1.w;
#pragma unroll
        for (int off = 8; off; off >>= 1) d += __shfl_down(d, off, 16);
        if (lane == 0) outS[grp] = d;
    }
}

// ---------------- fused final aggregation + per-graph readout -------------
__global__ void final_readout(const float* __restrict__ s, const unsigned int* __restrict__ pack,
                              const int2* __restrict__ range, const float* __restrict__ bfp,
                              float* __restrict__ out) {
    __shared__ float red[256];
    int g = blockIdx.x;
    float bf = bfp[0];
    float sum = 0.f;
    for (int n = threadIdx.x; n < NPG; n += blockDim.x) {
        int v = g * NPG + n;
        int2 r = range[v];
        float a = 0.f;
        for (int i = r.x; i < r.y; ++i) {
            unsigned int p = pack[i];
            a += __half2float(__ushort_as_half((unsigned short)(p & 0xffffu))) * s[p >> 16];
        }
        a += bf;
        sum += 1.f / (1.f + expf(-a));
    }
    red[threadIdx.x] = sum;
    __syncthreads();
    for (int t = 128; t > 0; t >>= 1) {
        if (threadIdx.x < t) red[threadIdx.x] += red[threadIdx.x + t];
        __syncthreads();
    }
    if (threadIdx.x == 0) out[g] = red[0] / (float)NPG;
}

extern "C" void kernel_launch(void* const* d_in, const int* in_sizes, int n_in,
                              void* d_out, int out_size, void* d_ws, size_t ws_size,
                              hipStream_t stream) {
    const float* X  = (const float*)d_in[0];
    const float* ew = (const float*)d_in[1];
    const float* W1 = (const float*)d_in[2];
    const float* b1 = (const float*)d_in[3];
    const float* W2 = (const float*)d_in[4];
    const float* b2 = (const float*)d_in[5];
    const float* Wf = (const float*)d_in[6];
    const float* bf = (const float*)d_in[7];
    const int* ei   = (const int*)d_in[8];
    const int* src  = ei;
    const int* dst  = ei + NEDGE;

    float* out = (float*)d_out;

    // workspace layout
    char* ws = (char*)d_ws;
    size_t off = 0;
    __half* bufA = (__half*)(ws + off); off += (size_t)N_NODES * DIM * 2;       // 12.8 MB
    __half* bufB = (__half*)(ws + off); off += (size_t)N_NODES * DIM * 2;       // 12.8 MB
    uint2* stage = (uint2*)(ws + off);  off += (size_t)NBUCKET * BCAP * 8;      // 8 MB
    unsigned int* pack = (unsigned int*)(ws + off); off += (size_t)NBUCKET * BCAP * 4; // 4 MB
    int2* range = (int2*)(ws + off);    off += (size_t)N_NODES * 8;             // 400 KB
    int* gCur   = (int*)(ws + off);     off += (size_t)256 * 4;
    _Float16* fragW1 = (_Float16*)(ws + off); off += (size_t)16384 * 2;         // 32 KB
    _Float16* fragW2 = (_Float16*)(ws + off); off += (size_t)16384 * 2;         // 32 KB
    float* s_node = (float*)(ws + off); off += (size_t)N_NODES * 4;

    const int TB = 256;
    const int SCAT_BLK = (NEDGE + CHUNK - 1) / CHUNK;     // 391
    const int GATHER_BLK = (N_NODES * 16 + TB - 1) / TB;  // 3125
    const int MFMA_BLK = (N_NODES + 127) / 128;           // 391

    // ---- prep: cursors + pre-swizzled W fragments (one launch) ----
    prep<<<129, TB, 0, stream>>>(W1, W2, fragW1, fragW2, gCur);
    // ---- CSR build (bucketed counting sort) ----
    bucket_scatter<<<SCAT_BLK, TB, 0, stream>>>(src, dst, ew, gCur, stage, NEDGE);
    bucket_build<<<NBUCKET, TB, 0, stream>>>(gCur, stage, pack, range);

    // ---- layer 1: h1 = relu(A(X@W1) + b1) ----
    gemm_mfma<float><<<MFMA_BLK, 512, 0, stream>>>(X, fragW1, bufA);
    gather_feat<0><<<GATHER_BLK, TB, 0, stream>>>(bufA, pack, range, b1,
                                                  nullptr, bufB, nullptr);
    // ---- layer 2 + Wf dot: s = relu(A(h1@W2) + b2) @ Wf ----
    gemm_mfma<__half><<<MFMA_BLK, 512, 0, stream>>>(bufB, fragW2, bufA);
    gather_feat<1><<<GATHER_BLK, TB, 0, stream>>>(bufA, pack, range, b2,
                                                  Wf, nullptr, s_node);
    // ---- final aggregation + readout (fused) ----
    final_readout<<<NGRAPH, TB, 0, stream>>>(s_node, pack, range, bf, out);
}

// Round 8
// 112.907 us; speedup vs baseline: 27.3083x; 1.1927x over previous
//
#include <hip/hip_runtime.h>
#include <hip/hip_fp16.h>

#define N_NODES 50000
#define DIM 128
#define NEDGE 800000
#define NGRAPH 100
#define NPG 500      // nodes per graph
#define NBUCKET 250  // dst buckets
#define NPB 200      // nodes per bucket (250*200 == 50000 exactly)
#define BCAP 4096    // padded slots per bucket (mean 3200, sd 56 -> safe)
#define CHUNK 2048   // edges per block in scatter pass
#define EPT (CHUNK / 256)

typedef _Float16 f16x8 __attribute__((ext_vector_type(8)));
typedef float f32x4 __attribute__((ext_vector_type(4)));
typedef float f32x2 __attribute__((ext_vector_type(2)));

// ---------------- fp8 helpers (OCP e4m3 HW converts) ----------------
__device__ inline float wgt(unsigned p) {
    return __half2float(__ushort_as_half((unsigned short)(p & 0xffffu)));
}
// accumulate 8 fp8 features (one row chunk) scaled by w
__device__ inline void accrow(uint2 q, float w, float* acc) {
    f32x2 f;
    f = __builtin_amdgcn_cvt_pk_f32_fp8((int)q.x, false); acc[0] = fmaf(w, f[0], acc[0]); acc[1] = fmaf(w, f[1], acc[1]);
    f = __builtin_amdgcn_cvt_pk_f32_fp8((int)q.x, true);  acc[2] = fmaf(w, f[0], acc[2]); acc[3] = fmaf(w, f[1], acc[3]);
    f = __builtin_amdgcn_cvt_pk_f32_fp8((int)q.y, false); acc[4] = fmaf(w, f[0], acc[4]); acc[5] = fmaf(w, f[1], acc[5]);
    f = __builtin_amdgcn_cvt_pk_f32_fp8((int)q.y, true);  acc[6] = fmaf(w, f[0], acc[6]); acc[7] = fmaf(w, f[1], acc[7]);
}
__device__ inline unsigned pack_fp8x4(float a, float b, float c, float d) {
    int v = __builtin_amdgcn_cvt_pk_fp8_f32(a, b, 0, false);   // bytes 0,1
    v = __builtin_amdgcn_cvt_pk_fp8_f32(c, d, v, true);        // bytes 2,3
    return (unsigned)v;
}

// ---------------- prep: cursor init + pre-swizzled fp16 W-fragments -------
// blocks 0..63: fragW1, 64..127: fragW2, 128: gCur init.
__global__ void prep(const float* __restrict__ W1, const float* __restrict__ W2,
                     _Float16* __restrict__ fragW1, _Float16* __restrict__ fragW2,
                     int* __restrict__ gCur) {
    const int b = blockIdx.x;
    if (b == 128) {
        int t = threadIdx.x;
        if (t < NBUCKET) gCur[t] = t * BCAP;
        return;
    }
    const float* W = (b < 64) ? W1 : W2;
    _Float16* F = (b < 64) ? fragW1 : fragW2;
    int idx = (b & 63) * 256 + threadIdx.x;   // 0..16383
    int j = idx & 7, l = (idx >> 3) & 63, kt = (idx >> 9) & 3, nt = idx >> 11;
    int k = kt * 32 + ((l >> 4) << 3) + j;
    int col = (nt << 4) + (l & 15);
    F[idx] = (_Float16)W[k * DIM + col];
}

// ---------------- pass 1: bucket edges by dst/NPB --------------
__global__ void bucket_scatter(const int* __restrict__ src, const int* __restrict__ dst,
                               const float* __restrict__ w, int* __restrict__ gCur,
                               uint2* __restrict__ stage, int E) {
    __shared__ int hist[NBUCKET];
    __shared__ int base[NBUCKET];
    for (int i = threadIdx.x; i < NBUCKET; i += 256) hist[i] = 0;
    __syncthreads();
    const int e0 = blockIdx.x * CHUNK;
    int myDst[EPT];
#pragma unroll
    for (int j = 0; j < EPT; ++j) {
        int e = e0 + j * 256 + threadIdx.x;
        int d = (e < E) ? dst[e] : -1;
        myDst[j] = d;
        if (d >= 0) atomicAdd(&hist[d / NPB], 1);
    }
    __syncthreads();
    for (int i = threadIdx.x; i < NBUCKET; i += 256)
        base[i] = atomicAdd(&gCur[i], hist[i]);   // reserve private run
    __syncthreads();
#pragma unroll
    for (int j = 0; j < EPT; ++j) {
        int d = myDst[j];
        if (d >= 0) {
            int e = e0 + j * 256 + threadIdx.x;
            int b = d / NPB;
            int p = atomicAdd(&base[b], 1);
            unsigned short wh = __half_as_ushort(__float2half_rn(w[e]));
            stage[p] = make_uint2(((unsigned)src[e] << 16) | (unsigned)wh,
                                  (unsigned)(d - b * NPB));
        }
    }
}

// ---------------- pass 2: per-bucket local CSR -----------------
__global__ void bucket_build(const int* __restrict__ gCur, const uint2* __restrict__ stage,
                             unsigned int* __restrict__ pack, int2* __restrict__ range) {
    __shared__ int lhist[NPB];
    __shared__ int lincl[256];
    __shared__ int lcur[NPB];
    const int b = blockIdx.x;
    const int t = threadIdx.x;
    const int cnt = gCur[b] - b * BCAP;
    for (int i = t; i < NPB; i += 256) lhist[i] = 0;
    __syncthreads();
    unsigned myX[BCAP / 256];
    int myLd[BCAP / 256];
#pragma unroll
    for (int j = 0; j < BCAP / 256; ++j) {
        int i = j * 256 + t;
        if (i < cnt) {
            uint2 r = stage[b * BCAP + i];
            myX[j] = r.x;
            myLd[j] = (int)r.y;
            atomicAdd(&lhist[r.y], 1);
        } else {
            myLd[j] = -1;
        }
    }
    __syncthreads();
    int h = (t < NPB) ? lhist[t] : 0;
    lincl[t] = h;
    __syncthreads();
    for (int off = 1; off < 256; off <<= 1) {
        int v = (t >= off) ? lincl[t - off] : 0;
        __syncthreads();
        lincl[t] += v;
        __syncthreads();
    }
    if (t < NPB) lcur[t] = lincl[t] - h;   // exclusive prefix
    __syncthreads();
#pragma unroll
    for (int j = 0; j < BCAP / 256; ++j) {
        if (myLd[j] >= 0) {
            int p = atomicAdd(&lcur[myLd[j]], 1);
            pack[b * BCAP + p] = myX[j];
        }
    }
    if (t < NPB) {
        int v = b * NPB + t;
        range[v] = make_int2(b * BCAP + lincl[t] - h, b * BCAP + lincl[t]);
    }
}

// ---------------- MFMA GEMM: C[n,128] = A[n,128] @ W[128,128] -> fp8 ------
__device__ inline f16x8 load_afrag_f32(const float* a) {
    float4 u0 = *(const float4*)a;
    float4 u1 = *(const float4*)(a + 4);
    f16x8 r;
    r[0] = (_Float16)u0.x; r[1] = (_Float16)u0.y; r[2] = (_Float16)u0.z; r[3] = (_Float16)u0.w;
    r[4] = (_Float16)u1.x; r[5] = (_Float16)u1.y; r[6] = (_Float16)u1.z; r[7] = (_Float16)u1.w;
    return r;
}
__device__ inline f16x8 load_afrag_fp8(const unsigned char* a) {
    uint2 q = *(const uint2*)a;
    f32x2 f0 = __builtin_amdgcn_cvt_pk_f32_fp8((int)q.x, false);
    f32x2 f1 = __builtin_amdgcn_cvt_pk_f32_fp8((int)q.x, true);
    f32x2 f2 = __builtin_amdgcn_cvt_pk_f32_fp8((int)q.y, false);
    f32x2 f3 = __builtin_amdgcn_cvt_pk_f32_fp8((int)q.y, true);
    f16x8 r;
    r[0] = (_Float16)f0[0]; r[1] = (_Float16)f0[1]; r[2] = (_Float16)f1[0]; r[3] = (_Float16)f1[1];
    r[4] = (_Float16)f2[0]; r[5] = (_Float16)f2[1]; r[6] = (_Float16)f3[0]; r[7] = (_Float16)f3[1];
    return r;
}

template <typename TIN>
__global__ __launch_bounds__(512) void gemm_mfma(const TIN* __restrict__ A,
                                                 const _Float16* __restrict__ fragWg,
                                                 unsigned char* __restrict__ C) {
    __shared__ __align__(16) _Float16 fragW[16384];   // 32 KB
    const int tid = threadIdx.x;
    for (int i = tid; i < 2048; i += 512)
        ((uint4*)fragW)[i] = ((const uint4*)fragWg)[i];
    __syncthreads();
    const int lane = tid & 63;
    const int wid = tid >> 6;
    const int row0 = blockIdx.x * 128 + wid * 16;
    if (row0 >= N_NODES) return;   // after sync: safe for tail waves
    const int arow = row0 + (lane & 15);
    const int koff = (lane >> 4) << 3;
    f32x4 acc[8] = {};
#pragma unroll
    for (int kt = 0; kt < 4; ++kt) {
        f16x8 a;
        const TIN* ap = A + (size_t)arow * DIM + kt * 32 + koff;
        if constexpr (sizeof(TIN) == 4) a = load_afrag_f32((const float*)ap);
        else                            a = load_afrag_fp8((const unsigned char*)ap);
#pragma unroll
        for (int nt = 0; nt < 8; ++nt) {
            f16x8 b = *(const f16x8*)&fragW[(((nt << 2) | kt) << 9) | (lane << 3)];
            acc[nt] = __builtin_amdgcn_mfma_f32_16x16x32_f16(a, b, acc[nt], 0, 0, 0);
        }
    }
    const int crow = row0 + ((lane >> 4) << 2);
    const int ccol = lane & 15;
#pragma unroll
    for (int nt = 0; nt < 8; ++nt) {
#pragma unroll
        for (int r = 0; r < 4; ++r) {
            int v8 = __builtin_amdgcn_cvt_pk_fp8_f32(acc[nt][r], acc[nt][r], 0, false);
            C[(size_t)(crow + r) * DIM + (nt << 4) + ccol] = (unsigned char)(v8 & 0xff);
        }
    }
}

// ---------------- CSR gather + fused epilogue (fp8 msg) ------------------
// 16-lane group per node, uint2 (8 fp8) per lane, 4-deep edge unroll.
// MODE 0: outF_row = fp8(relu(agg + bias))
// MODE 1: h = relu(agg + bias); outS[v] = dot(h, wf)
template <int MODE>
__global__ void gather_feat(const unsigned char* __restrict__ msg,
                            const unsigned int* __restrict__ pack,
                            const int2* __restrict__ range, const float* __restrict__ bias,
                            const float* __restrict__ wf, unsigned char* __restrict__ outF,
                            float* __restrict__ outS) {
    int gid = blockIdx.x * blockDim.x + threadIdx.x;
    int grp = gid >> 4, lane = gid & 15;
    if (grp >= N_NODES) return;
    int2 r = range[grp];
    int beg = r.x, end = r.y;
    float acc[8] = {};
    int i = beg;
    for (; i + 3 < end; i += 4) {
        unsigned p0 = pack[i], p1 = pack[i + 1], p2 = pack[i + 2], p3 = pack[i + 3];
        uint2 q0 = ((const uint2*)(msg + (size_t)(p0 >> 16) * DIM))[lane];
        uint2 q1 = ((const uint2*)(msg + (size_t)(p1 >> 16) * DIM))[lane];
        uint2 q2 = ((const uint2*)(msg + (size_t)(p2 >> 16) * DIM))[lane];
        uint2 q3 = ((const uint2*)(msg + (size_t)(p3 >> 16) * DIM))[lane];
        accrow(q0, wgt(p0), acc);
        accrow(q1, wgt(p1), acc);
        accrow(q2, wgt(p2), acc);
        accrow(q3, wgt(p3), acc);
    }
    for (; i < end; ++i) {
        unsigned p = pack[i];
        uint2 q = ((const uint2*)(msg + (size_t)(p >> 16) * DIM))[lane];
        accrow(q, wgt(p), acc);
    }
    float4 b0 = ((const float4*)bias)[2 * lane];
    float4 b1 = ((const float4*)bias)[2 * lane + 1];
    acc[0] = fmaxf(acc[0] + b0.x, 0.f); acc[1] = fmaxf(acc[1] + b0.y, 0.f);
    acc[2] = fmaxf(acc[2] + b0.z, 0.f); acc[3] = fmaxf(acc[3] + b0.w, 0.f);
    acc[4] = fmaxf(acc[4] + b1.x, 0.f); acc[5] = fmaxf(acc[5] + b1.y, 0.f);
    acc[6] = fmaxf(acc[6] + b1.z, 0.f); acc[7] = fmaxf(acc[7] + b1.w, 0.f);
    if (MODE == 0) {
        uint2 o;
        o.x = pack_fp8x4(acc[0], acc[1], acc[2], acc[3]);
        o.y = pack_fp8x4(acc[4], acc[5], acc[6], acc[7]);
        ((uint2*)(outF + (size_t)grp * DIM))[lane] = o;
    } else {
        float4 f0 = ((const float4*)wf)[2 * lane];
        float4 f1 = ((const float4*)wf)[2 * lane + 1];
        float d = acc[0] * f0.x + acc[1] * f0.y + acc[2] * f0.z + acc[3] * f0.w
                + acc[4] * f1.x + acc[5] * f1.y + acc[6] * f1.z + acc[7] * f1.w;
#pragma unroll
        for (int off = 8; off; off >>= 1) d += __shfl_down(d, off, 16);
        if (lane == 0) outS[grp] = d;
    }
}

// ---------------- fused final aggregation + per-graph readout -------------
__global__ void final_readout(const float* __restrict__ s, const unsigned int* __restrict__ pack,
                              const int2* __restrict__ range, const float* __restrict__ bfp,
                              float* __restrict__ out) {
    __shared__ float red[256];
    int g = blockIdx.x;
    float bf = bfp[0];
    float sum = 0.f;
    for (int n = threadIdx.x; n < NPG; n += blockDim.x) {
        int v = g * NPG + n;
        int2 r = range[v];
        float a = 0.f;
        for (int i = r.x; i < r.y; ++i) {
            unsigned int p = pack[i];
            a += wgt(p) * s[p >> 16];
        }
        a += bf;
        sum += 1.f / (1.f + expf(-a));
    }
    red[threadIdx.x] = sum;
    __syncthreads();
    for (int t = 128; t > 0; t >>= 1) {
        if (threadIdx.x < t) red[threadIdx.x] += red[threadIdx.x + t];
        __syncthreads();
    }
    if (threadIdx.x == 0) out[g] = red[0] / (float)NPG;
}

extern "C" void kernel_launch(void* const* d_in, const int* in_sizes, int n_in,
                              void* d_out, int out_size, void* d_ws, size_t ws_size,
                              hipStream_t stream) {
    const float* X  = (const float*)d_in[0];
    const float* ew = (const float*)d_in[1];
    const float* W1 = (const float*)d_in[2];
    const float* b1 = (const float*)d_in[3];
    const float* W2 = (const float*)d_in[4];
    const float* b2 = (const float*)d_in[5];
    const float* Wf = (const float*)d_in[6];
    const float* bf = (const float*)d_in[7];
    const int* ei   = (const int*)d_in[8];
    const int* src  = ei;
    const int* dst  = ei + NEDGE;

    float* out = (float*)d_out;

    // workspace layout
    char* ws = (char*)d_ws;
    size_t off = 0;
    unsigned char* bufA = (unsigned char*)(ws + off); off += (size_t)N_NODES * DIM;  // 6.4 MB (fp8)
    unsigned char* bufB = (unsigned char*)(ws + off); off += (size_t)N_NODES * DIM;  // 6.4 MB (fp8)
    uint2* stage = (uint2*)(ws + off);  off += (size_t)NBUCKET * BCAP * 8;           // 8 MB
    unsigned int* pack = (unsigned int*)(ws + off); off += (size_t)NBUCKET * BCAP * 4; // 4 MB
    int2* range = (int2*)(ws + off);    off += (size_t)N_NODES * 8;                  // 400 KB
    int* gCur   = (int*)(ws + off);     off += (size_t)256 * 4;
    _Float16* fragW1 = (_Float16*)(ws + off); off += (size_t)16384 * 2;              // 32 KB
    _Float16* fragW2 = (_Float16*)(ws + off); off += (size_t)16384 * 2;              // 32 KB
    float* s_node = (float*)(ws + off); off += (size_t)N_NODES * 4;

    const int TB = 256;
    const int SCAT_BLK = (NEDGE + CHUNK - 1) / CHUNK;     // 391
    const int GATHER_BLK = (N_NODES * 16 + TB - 1) / TB;  // 3125
    const int MFMA_BLK = (N_NODES + 127) / 128;           // 391

    // ---- prep: cursors + pre-swizzled W fragments (one launch) ----
    prep<<<129, TB, 0, stream>>>(W1, W2, fragW1, fragW2, gCur);
    // ---- CSR build (bucketed counting sort) ----
    bucket_scatter<<<SCAT_BLK, TB, 0, stream>>>(src, dst, ew, gCur, stage, NEDGE);
    bucket_build<<<NBUCKET, TB, 0, stream>>>(gCur, stage, pack, range);

    // ---- layer 1: h1 = relu(A(X@W1) + b1) ----
    gemm_mfma<float><<<MFMA_BLK, 512, 0, stream>>>(X, fragW1, bufA);
    gather_feat<0><<<GATHER_BLK, TB, 0, stream>>>(bufA, pack, range, b1,
                                                  nullptr, bufB, nullptr);
    // ---- layer 2 + Wf dot: s = relu(A(h1@W2) + b2) @ Wf ----
    gemm_mfma<unsigned char><<<MFMA_BLK, 512, 0, stream>>>(bufB, fragW2, bufA);
    gather_feat<1><<<GATHER_BLK, TB, 0, stream>>>(bufA, pack, range, b2,
                                                  Wf, nullptr, s_node);
    // ---- final aggregation + readout (fused) ----
    final_readout<<<NGRAPH, TB, 0, stream>>>(s_node, pack, range, bf, out);
}

// Round 9
// 106.902 us; speedup vs baseline: 28.8423x; 1.0562x over previous
//
#include <hip/hip_runtime.h>
#include <hip/hip_fp16.h>

#define N_NODES 50000
#define DIM 128
#define NEDGE 800000
#define NGRAPH 100
#define NPG 500      // nodes per graph
#define NBUCKET 250  // dst buckets
#define NPB 200      // nodes per bucket (250*200 == 50000 exactly)
#define BCAP 4096    // padded slots per bucket (mean 3200, sd 56 -> safe)
#define CHUNK 2048   // edges per block in scatter pass
#define EPT (CHUNK / 256)

typedef _Float16 f16x8 __attribute__((ext_vector_type(8)));
typedef float f32x4 __attribute__((ext_vector_type(4)));
typedef float f32x2 __attribute__((ext_vector_type(2)));

// ---------------- fp8 helpers (OCP e4m3 HW converts) ----------------
__device__ inline float wgt(unsigned p) {
    return __half2float(__ushort_as_half((unsigned short)(p & 0xffffu)));
}
__device__ inline void accrow(uint2 q, float w, float* acc) {
    f32x2 f;
    f = __builtin_amdgcn_cvt_pk_f32_fp8((int)q.x, false); acc[0] = fmaf(w, f[0], acc[0]); acc[1] = fmaf(w, f[1], acc[1]);
    f = __builtin_amdgcn_cvt_pk_f32_fp8((int)q.x, true);  acc[2] = fmaf(w, f[0], acc[2]); acc[3] = fmaf(w, f[1], acc[3]);
    f = __builtin_amdgcn_cvt_pk_f32_fp8((int)q.y, false); acc[4] = fmaf(w, f[0], acc[4]); acc[5] = fmaf(w, f[1], acc[5]);
    f = __builtin_amdgcn_cvt_pk_f32_fp8((int)q.y, true);  acc[6] = fmaf(w, f[0], acc[6]); acc[7] = fmaf(w, f[1], acc[7]);
}
__device__ inline unsigned pack_fp8x4(float a, float b, float c, float d) {
    int v = __builtin_amdgcn_cvt_pk_fp8_f32(a, b, 0, false);
    v = __builtin_amdgcn_cvt_pk_fp8_f32(c, d, v, true);
    return (unsigned)v;
}

// ---------------- prep: cursor init + pre-swizzled fp16 W-fragments -------
__global__ void prep(const float* __restrict__ W1, const float* __restrict__ W2,
                     _Float16* __restrict__ fragW1, _Float16* __restrict__ fragW2,
                     int* __restrict__ gCur) {
    const int b = blockIdx.x;
    if (b == 128) {
        int t = threadIdx.x;
        if (t < NBUCKET) gCur[t] = t * BCAP;
        return;
    }
    const float* W = (b < 64) ? W1 : W2;
    _Float16* F = (b < 64) ? fragW1 : fragW2;
    int idx = (b & 63) * 256 + threadIdx.x;   // 0..16383
    int j = idx & 7, l = (idx >> 3) & 63, kt = (idx >> 9) & 3, nt = idx >> 11;
    int k = kt * 32 + ((l >> 4) << 3) + j;
    int col = (nt << 4) + (l & 15);
    F[idx] = (_Float16)W[k * DIM + col];
}

// ---------------- pass 1: bucket edges by dst/NPB --------------
__global__ void bucket_scatter(const int* __restrict__ src, const int* __restrict__ dst,
                               const float* __restrict__ w, int* __restrict__ gCur,
                               uint2* __restrict__ stage, int E) {
    __shared__ int hist[NBUCKET];
    __shared__ int base[NBUCKET];
    for (int i = threadIdx.x; i < NBUCKET; i += 256) hist[i] = 0;
    __syncthreads();
    const int e0 = blockIdx.x * CHUNK;
    int myDst[EPT];
#pragma unroll
    for (int j = 0; j < EPT; ++j) {
        int e = e0 + j * 256 + threadIdx.x;
        int d = (e < E) ? dst[e] : -1;
        myDst[j] = d;
        if (d >= 0) atomicAdd(&hist[d / NPB], 1);
    }
    __syncthreads();
    for (int i = threadIdx.x; i < NBUCKET; i += 256)
        base[i] = atomicAdd(&gCur[i], hist[i]);   // reserve private run
    __syncthreads();
#pragma unroll
    for (int j = 0; j < EPT; ++j) {
        int d = myDst[j];
        if (d >= 0) {
            int e = e0 + j * 256 + threadIdx.x;
            int b = d / NPB;
            int p = atomicAdd(&base[b], 1);
            unsigned short wh = __half_as_ushort(__float2half_rn(w[e]));
            stage[p] = make_uint2(((unsigned)src[e] << 16) | (unsigned)wh,
                                  (unsigned)(d - b * NPB));
        }
    }
}

// ---------------- MFMA GEMM body (one 128-row tile) -----------------------
__device__ inline f16x8 load_afrag_f32(const float* a) {
    float4 u0 = *(const float4*)a;
    float4 u1 = *(const float4*)(a + 4);
    f16x8 r;
    r[0] = (_Float16)u0.x; r[1] = (_Float16)u0.y; r[2] = (_Float16)u0.z; r[3] = (_Float16)u0.w;
    r[4] = (_Float16)u1.x; r[5] = (_Float16)u1.y; r[6] = (_Float16)u1.z; r[7] = (_Float16)u1.w;
    return r;
}
__device__ inline f16x8 load_afrag_fp8(const unsigned char* a) {
    uint2 q = *(const uint2*)a;
    f32x2 f0 = __builtin_amdgcn_cvt_pk_f32_fp8((int)q.x, false);
    f32x2 f1 = __builtin_amdgcn_cvt_pk_f32_fp8((int)q.x, true);
    f32x2 f2 = __builtin_amdgcn_cvt_pk_f32_fp8((int)q.y, false);
    f32x2 f3 = __builtin_amdgcn_cvt_pk_f32_fp8((int)q.y, true);
    f16x8 r;
    r[0] = (_Float16)f0[0]; r[1] = (_Float16)f0[1]; r[2] = (_Float16)f1[0]; r[3] = (_Float16)f1[1];
    r[4] = (_Float16)f2[0]; r[5] = (_Float16)f2[1]; r[6] = (_Float16)f3[0]; r[7] = (_Float16)f3[1];
    return r;
}

template <typename TIN>
__device__ inline void gemm_tile(const TIN* __restrict__ A, const _Float16* fragW,
                                 unsigned char* __restrict__ C, int blk, int tid) {
    const int lane = tid & 63;
    const int wid = tid >> 6;
    const int row0 = blk * 128 + wid * 16;
    if (row0 >= N_NODES) return;
    const int arow = row0 + (lane & 15);
    const int koff = (lane >> 4) << 3;
    f32x4 acc[8] = {};
#pragma unroll
    for (int kt = 0; kt < 4; ++kt) {
        f16x8 a;
        const TIN* ap = A + (size_t)arow * DIM + kt * 32 + koff;
        if constexpr (sizeof(TIN) == 4) a = load_afrag_f32((const float*)ap);
        else                            a = load_afrag_fp8((const unsigned char*)ap);
#pragma unroll
        for (int nt = 0; nt < 8; ++nt) {
            f16x8 b = *(const f16x8*)&fragW[(((nt << 2) | kt) << 9) | (lane << 3)];
            acc[nt] = __builtin_amdgcn_mfma_f32_16x16x32_f16(a, b, acc[nt], 0, 0, 0);
        }
    }
    const int crow = row0 + ((lane >> 4) << 2);
    const int ccol = lane & 15;
#pragma unroll
    for (int nt = 0; nt < 8; ++nt) {
#pragma unroll
        for (int r = 0; r < 4; ++r) {
            int v8 = __builtin_amdgcn_cvt_pk_fp8_f32(acc[nt][r], acc[nt][r], 0, false);
            C[(size_t)(crow + r) * DIM + (nt << 4) + ccol] = (unsigned char)(v8 & 0xff);
        }
    }
}

// ---------------- standalone gemm (layer 2) ----------------
template <typename TIN>
__global__ __launch_bounds__(512) void gemm_mfma(const TIN* __restrict__ A,
                                                 const _Float16* __restrict__ fragWg,
                                                 unsigned char* __restrict__ C) {
    __shared__ __align__(16) _Float16 fragW[16384];   // 32 KB
    const int tid = threadIdx.x;
    for (int i = tid; i < 2048; i += 512)
        ((uint4*)fragW)[i] = ((const uint4*)fragWg)[i];
    __syncthreads();
    gemm_tile<TIN>(A, fragW, C, blockIdx.x, tid);
}

// ---------------- fused: gemm1 (blocks < MB) + bucket_build (blocks >= MB) -
#define MFMA_BLK ((N_NODES + 127) / 128)   // 391
__global__ __launch_bounds__(512) void gemm1_build(
        const float* __restrict__ A, const _Float16* __restrict__ fragWg,
        unsigned char* __restrict__ C, const int* __restrict__ gCur,
        const uint2* __restrict__ stage, unsigned int* __restrict__ pack,
        int2* __restrict__ range) {
    __shared__ __align__(16) _Float16 fragW[16384];   // 32 KB (gemm path)
    __shared__ int lhist[NPB];
    __shared__ int lincl[256];
    __shared__ int lcur[NPB];
    const int tid = threadIdx.x;
    if (blockIdx.x < MFMA_BLK) {
        for (int i = tid; i < 2048; i += 512)
            ((uint4*)fragW)[i] = ((const uint4*)fragWg)[i];
        __syncthreads();
        gemm_tile<float>(A, fragW, C, blockIdx.x, tid);
        return;
    }
    // ---- bucket_build path (512 threads, 8 items each) ----
    const int b = blockIdx.x - MFMA_BLK;
    const int t = tid;
    const int cnt = gCur[b] - b * BCAP;
    for (int i = t; i < NPB; i += 512) lhist[i] = 0;
    __syncthreads();
    unsigned myX[BCAP / 512];
    int myLd[BCAP / 512];
#pragma unroll
    for (int j = 0; j < BCAP / 512; ++j) {
        int i = j * 512 + t;
        if (i < cnt) {
            uint2 r = stage[b * BCAP + i];
            myX[j] = r.x;
            myLd[j] = (int)r.y;
            atomicAdd(&lhist[r.y], 1);
        } else {
            myLd[j] = -1;
        }
    }
    __syncthreads();
    int h = (t < NPB) ? lhist[t] : 0;
    if (t < 256) lincl[t] = h;
    __syncthreads();
    for (int off = 1; off < 256; off <<= 1) {
        int v = (t >= off && t < 256) ? lincl[t - off] : 0;
        __syncthreads();
        if (t < 256) lincl[t] += v;
        __syncthreads();
    }
    if (t < NPB) lcur[t] = lincl[t] - h;   // exclusive prefix
    __syncthreads();
#pragma unroll
    for (int j = 0; j < BCAP / 512; ++j) {
        if (myLd[j] >= 0) {
            int p = atomicAdd(&lcur[myLd[j]], 1);
            pack[b * BCAP + p] = myX[j];
        }
    }
    if (t < NPB) {
        int v = b * NPB + t;
        range[v] = make_int2(b * BCAP + lincl[t] - h, b * BCAP + lincl[t]);
    }
}

// ---------------- CSR gather + fused epilogue (fp8 msg) ------------------
// 16-lane group per node, uint2 (8 fp8) per lane, 8-deep edge unroll.
template <int MODE>
__global__ void gather_feat(const unsigned char* __restrict__ msg,
                            const unsigned int* __restrict__ pack,
                            const int2* __restrict__ range, const float* __restrict__ bias,
                            const float* __restrict__ wf, unsigned char* __restrict__ outF,
                            float* __restrict__ outS) {
    int gid = blockIdx.x * blockDim.x + threadIdx.x;
    int grp = gid >> 4, lane = gid & 15;
    if (grp >= N_NODES) return;
    int2 r = range[grp];
    int beg = r.x, end = r.y;
    float acc[8] = {};
    int i = beg;
    for (; i + 7 < end; i += 8) {      // 8 independent gather chains
        unsigned p[8];
        uint2 q[8];
#pragma unroll
        for (int j = 0; j < 8; ++j) p[j] = pack[i + j];
#pragma unroll
        for (int j = 0; j < 8; ++j)
            q[j] = ((const uint2*)(msg + (size_t)(p[j] >> 16) * DIM))[lane];
#pragma unroll
        for (int j = 0; j < 8; ++j) accrow(q[j], wgt(p[j]), acc);
    }
    for (; i + 3 < end; i += 4) {
        unsigned p0 = pack[i], p1 = pack[i + 1], p2 = pack[i + 2], p3 = pack[i + 3];
        uint2 q0 = ((const uint2*)(msg + (size_t)(p0 >> 16) * DIM))[lane];
        uint2 q1 = ((const uint2*)(msg + (size_t)(p1 >> 16) * DIM))[lane];
        uint2 q2 = ((const uint2*)(msg + (size_t)(p2 >> 16) * DIM))[lane];
        uint2 q3 = ((const uint2*)(msg + (size_t)(p3 >> 16) * DIM))[lane];
        accrow(q0, wgt(p0), acc);
        accrow(q1, wgt(p1), acc);
        accrow(q2, wgt(p2), acc);
        accrow(q3, wgt(p3), acc);
    }
    for (; i < end; ++i) {
        unsigned p = pack[i];
        uint2 q = ((const uint2*)(msg + (size_t)(p >> 16) * DIM))[lane];
        accrow(q, wgt(p), acc);
    }
    float4 b0 = ((const float4*)bias)[2 * lane];
    float4 b1 = ((const float4*)bias)[2 * lane + 1];
    acc[0] = fmaxf(acc[0] + b0.x, 0.f); acc[1] = fmaxf(acc[1] + b0.y, 0.f);
    acc[2] = fmaxf(acc[2] + b0.z, 0.f); acc[3] = fmaxf(acc[3] + b0.w, 0.f);
    acc[4] = fmaxf(acc[4] + b1.x, 0.f); acc[5] = fmaxf(acc[5] + b1.y, 0.f);
    acc[6] = fmaxf(acc[6] + b1.z, 0.f); acc[7] = fmaxf(acc[7] + b1.w, 0.f);
    if (MODE == 0) {
        uint2 o;
        o.x = pack_fp8x4(acc[0], acc[1], acc[2], acc[3]);
        o.y = pack_fp8x4(acc[4], acc[5], acc[6], acc[7]);
        ((uint2*)(outF + (size_t)grp * DIM))[lane] = o;
    } else {
        float4 f0 = ((const float4*)wf)[2 * lane];
        float4 f1 = ((const float4*)wf)[2 * lane + 1];
        float d = acc[0] * f0.x + acc[1] * f0.y + acc[2] * f0.z + acc[3] * f0.w
                + acc[4] * f1.x + acc[5] * f1.y + acc[6] * f1.z + acc[7] * f1.w;
#pragma unroll
        for (int off = 8; off; off >>= 1) d += __shfl_down(d, off, 16);
        if (lane == 0) outS[grp] = d;
    }
}

// ---------------- fused final aggregation + per-graph readout -------------
__global__ void final_readout(const float* __restrict__ s, const unsigned int* __restrict__ pack,
                              const int2* __restrict__ range, const float* __restrict__ bfp,
                              float* __restrict__ out) {
    __shared__ float red[256];
    int g = blockIdx.x;
    float bf = bfp[0];
    float sum = 0.f;
    for (int n = threadIdx.x; n < NPG; n += blockDim.x) {
        int v = g * NPG + n;
        int2 r = range[v];
        float a = 0.f;
        for (int i = r.x; i < r.y; ++i) {
            unsigned int p = pack[i];
            a += wgt(p) * s[p >> 16];
        }
        a += bf;
        sum += 1.f / (1.f + expf(-a));
    }
    red[threadIdx.x] = sum;
    __syncthreads();
    for (int t = 128; t > 0; t >>= 1) {
        if (threadIdx.x < t) red[threadIdx.x] += red[threadIdx.x + t];
        __syncthreads();
    }
    if (threadIdx.x == 0) out[g] = red[0] / (float)NPG;
}

extern "C" void kernel_launch(void* const* d_in, const int* in_sizes, int n_in,
                              void* d_out, int out_size, void* d_ws, size_t ws_size,
                              hipStream_t stream) {
    const float* X  = (const float*)d_in[0];
    const float* ew = (const float*)d_in[1];
    const float* W1 = (const float*)d_in[2];
    const float* b1 = (const float*)d_in[3];
    const float* W2 = (const float*)d_in[4];
    const float* b2 = (const float*)d_in[5];
    const float* Wf = (const float*)d_in[6];
    const float* bf = (const float*)d_in[7];
    const int* ei   = (const int*)d_in[8];
    const int* src  = ei;
    const int* dst  = ei + NEDGE;

    float* out = (float*)d_out;

    // workspace layout
    char* ws = (char*)d_ws;
    size_t off = 0;
    unsigned char* bufA = (unsigned char*)(ws + off); off += (size_t)N_NODES * DIM;  // 6.4 MB
    unsigned char* bufB = (unsigned char*)(ws + off); off += (size_t)N_NODES * DIM;  // 6.4 MB
    uint2* stage = (uint2*)(ws + off);  off += (size_t)NBUCKET * BCAP * 8;           // 8 MB
    unsigned int* pack = (unsigned int*)(ws + off); off += (size_t)NBUCKET * BCAP * 4; // 4 MB
    int2* range = (int2*)(ws + off);    off += (size_t)N_NODES * 8;                  // 400 KB
    int* gCur   = (int*)(ws + off);     off += (size_t)256 * 4;
    _Float16* fragW1 = (_Float16*)(ws + off); off += (size_t)16384 * 2;              // 32 KB
    _Float16* fragW2 = (_Float16*)(ws + off); off += (size_t)16384 * 2;              // 32 KB
    float* s_node = (float*)(ws + off); off += (size_t)N_NODES * 4;

    const int TB = 256;
    const int SCAT_BLK = (NEDGE + CHUNK - 1) / CHUNK;     // 391
    const int GATHER_BLK = (N_NODES * 16 + TB - 1) / TB;  // 3125

    // ---- prep: cursors + pre-swizzled W fragments ----
    prep<<<129, TB, 0, stream>>>(W1, W2, fragW1, fragW2, gCur);
    // ---- CSR pass 1 ----
    bucket_scatter<<<SCAT_BLK, TB, 0, stream>>>(src, dst, ew, gCur, stage, NEDGE);
    // ---- layer-1 GEMM fused with CSR pass 2 (independent work) ----
    gemm1_build<<<MFMA_BLK + NBUCKET, 512, 0, stream>>>(X, fragW1, bufA, gCur,
                                                        stage, pack, range);
    // ---- layer 1 gather: h1 = relu(A(X@W1) + b1) ----
    gather_feat<0><<<GATHER_BLK, TB, 0, stream>>>(bufA, pack, range, b1,
                                                  nullptr, bufB, nullptr);
    // ---- layer 2 + Wf dot ----
    gemm_mfma<unsigned char><<<MFMA_BLK, 512, 0, stream>>>(bufB, fragW2, bufA);
    gather_feat<1><<<GATHER_BLK, TB, 0, stream>>>(bufA, pack, range, b2,
                                                  Wf, nullptr, s_node);
    // ---- final aggregation + readout (fused) ----
    final_readout<<<NGRAPH, TB, 0, stream>>>(s_node, pack, range, bf, out);
}